// Round 5
// baseline (14338.069 us; speedup 1.0000x reference)
//
#include <hip/hip_runtime.h>

typedef float v4 __attribute__((ext_vector_type(4)));
typedef unsigned short u16;
typedef unsigned int u32;

#define DEVI __device__ __forceinline__

namespace {

constexpr int B = 64, C = 64, NPT = 500, T0 = 13, SC = 256, EC = 512, PR = 12;
constexpr size_t SLOT = (size_t)B * C * NPT;  // 2,048,000 elems per time slice

// sizes (bytes)
constexpr size_t SZ_A    = 13 * SLOT * 2;            // 53,248,000  x ping (bf16)
constexpr size_t SZ_Bb   = 12 * SLOT * 2;            // 49,152,000  x pong (bf16)
constexpr size_t SZ_XA12 = 12 * SLOT * 2;            // 49,152,000  gated (bf16, batched)
constexpr size_t SZ_XA1  = SLOT * 2;                 //  4,096,000  gated (bf16, 1 slot)
constexpr size_t SZ_SK   = (size_t)SC * B * NPT * 4; // 32,768,000  skip acc f32
constexpr size_t SZ_ST   = 1024;                     // f64[128]
constexpr size_t SZ_W    = (size_t)(65536 + 65536 + 131072 + 65536 + 131072) * 4;

constexpr size_t WS_FAST = SZ_A + SZ_Bb + SZ_XA12 + SZ_SK + SZ_ST + SZ_W; // 186,156,032
constexpr size_t WS_LEG  = SZ_A + SZ_XA1 + SZ_SK + SZ_ST + SZ_W;          //  91,948,032

DEVI float sigm(float x) { return 1.f / (1.f + expf(-x)); }
DEVI float bf2f(u16 u) { u32 x = ((u32)u) << 16; float f; __builtin_memcpy(&f, &x, 4); return f; }
DEVI u16 f2bf(float f) { u32 x; __builtin_memcpy(&x, &f, 4); return (u16)((x + 0x7FFF + ((x >> 16) & 1)) >> 16); }

// ---------------- debug: report ws_size (MB) through the output ----------------
__global__ void k_debug_ws(float* __restrict__ out, float val) {
  int i = blockIdx.x * 256 + threadIdx.x;
  if (i < B * PR * NPT) out[i] = val;
}

// ---------------- weight repack ----------------
__global__ void k_prep(const float* __restrict__ fw, const float* __restrict__ gw,
                       const float* __restrict__ sw, const float* __restrict__ gcw,
                       const float* __restrict__ o1w,
                       float* __restrict__ WF, float* __restrict__ WG,
                       float* __restrict__ SWT, float* __restrict__ GWT,
                       float* __restrict__ W1T) {
  int i = blockIdx.x * 256 + threadIdx.x;
  if (i < 65536) {  // [l][tap][c][cp] <- fw[((l*64+cp)*64+c)*2+tap]
    int cp = i & 63, c = (i >> 6) & 63, tap = (i >> 12) & 1, l = i >> 13;
    int g = ((l * 64 + cp) * 64 + c) * 2 + tap;
    WF[i] = fw[g];
    WG[i] = gw[g];
  }
  int j = i - 131072;
  if (j >= 0 && j < 131072) {  // [l][c][o] <- sw[(l*256+o)*64+c]
    int o = j & 255, cl = (j >> 8) & 63, l = j >> 14;
    SWT[j] = sw[(l * 256 + o) * 64 + cl];
  }
  int k2 = i - 262144;
  if (k2 >= 0 && k2 < 65536) {  // [l][kc][o] <- gcw[(l*64+o)*128+kc]
    int o = k2 & 63, kc = (k2 >> 6) & 127, l = k2 >> 13;
    GWT[k2] = gcw[(l * 64 + o) * 128 + kc];
  }
  int m = i - 327680;
  if (m >= 0 && m < 131072) {  // [o][e] <- o1w[e*256+o]
    int e = m & 511, o = m >> 9;
    W1T[m] = o1w[e * 256 + o];
  }
}

// ---------------- enter: [B,12,N,2] -> Xbf[t][b][c][n], t=0 is left-pad ----------------
__global__ void k_enter(const float* __restrict__ in, const float* __restrict__ ew,
                        const float* __restrict__ eb, u16* __restrict__ X) {
  size_t idx = (size_t)blockIdx.x * 256 + threadIdx.x;
  if (idx >= 13 * SLOT) return;
  int t = (int)(idx / SLOT);
  size_t r = idx % SLOT;
  int n = (int)(r % NPT);
  int c = (int)((r / NPT) % C);
  int b = (int)(r / ((size_t)NPT * C));
  float v = eb[c];
  if (t > 0) {
    const float* ip = in + (((size_t)b * 12 + (t - 1)) * NPT + n) * 2;
    v += ew[c * 2] * ip[0] + ew[c * 2 + 1] * ip[1];
  }
  X[idx] = f2bf(v);
}

// ---------------- gated conv: grid (8, nT, B); slice t = t0 + blockIdx.y ----------------
// writes XA slot blockIdx.y (bf16)
__global__ __launch_bounds__(256, 4) void k_gatedconv(
    const u16* __restrict__ X, u16* __restrict__ XA,
    const float* __restrict__ WFl, const float* __restrict__ bf,
    const float* __restrict__ WGl, const float* __restrict__ bg,
    int t0, int d) {
  __shared__ __align__(16) float wfs[2048];  // [tap][cc16][cp64] current chunk
  __shared__ __align__(16) float wgs[2048];
  __shared__ __align__(16) float xs[2048];   // [tap][cc16][n64]
  const int tx = threadIdx.x, ty = threadIdx.y;
  const int tid = ty * 16 + tx;
  const int n0 = blockIdx.x * 64;
  const int ts = blockIdx.y;
  const int b = blockIdx.z;
  const int t = t0 + ts;
  v4 f[4] = {}, g[4] = {};
  for (int c0 = 0; c0 < 64; c0 += 16) {
    __syncthreads();
    for (int i = tid; i < 2048; i += 256) {
      int tap = i >> 10, cc = (i >> 6) & 15, j = i & 63;
      int src = tap * 4096 + (c0 + cc) * 64 + j;
      wfs[i] = WFl[src];
      wgs[i] = WGl[src];
    }
    for (int i = tid; i < 2048; i += 256) {
      int nn = i & 63, cc = (i >> 6) & 15, tap = i >> 10;
      int n = n0 + nn;
      xs[i] = (n < NPT)
          ? bf2f(X[(size_t)(t + tap * d) * SLOT + ((size_t)b * C + c0 + cc) * NPT + n])
          : 0.f;
    }
    __syncthreads();
#pragma unroll
    for (int cc = 0; cc < 16; ++cc) {
      v4 xv0 = *(const v4*)&xs[cc * 64 + tx * 4];
      v4 xv1 = *(const v4*)&xs[1024 + cc * 64 + tx * 4];
      v4 wf0 = *(const v4*)&wfs[cc * 64 + ty * 4];
      v4 wf1 = *(const v4*)&wfs[1024 + cc * 64 + ty * 4];
      v4 wg0 = *(const v4*)&wgs[cc * 64 + ty * 4];
      v4 wg1 = *(const v4*)&wgs[1024 + cc * 64 + ty * 4];
#pragma unroll
      for (int r = 0; r < 4; ++r) {
        f[r] += wf0[r] * xv0 + wf1[r] * xv1;
        g[r] += wg0[r] * xv0 + wg1[r] * xv1;
      }
    }
  }
  const int cp = ty * 4;
  const int n = n0 + tx * 4;
  if (n < NPT) {
#pragma unroll
    for (int r = 0; r < 4; ++r) {
      float fb = bf[cp + r], gb2 = bg[cp + r];
      size_t ob = (size_t)ts * SLOT + ((size_t)b * C + cp + r) * NPT + n;
      ushort4 ov;
      ov.x = f2bf(tanhf(f[r][0] + fb) * sigm(g[r][0] + gb2));
      ov.y = f2bf(tanhf(f[r][1] + fb) * sigm(g[r][1] + gb2));
      ov.z = f2bf(tanhf(f[r][2] + fb) * sigm(g[r][2] + gb2));
      ov.w = f2bf(tanhf(f[r][3] + fb) * sigm(g[r][3] + gb2));
      *(ushort4*)&XA[ob] = ov;
    }
  }
}

// ---------------- skip GEMM on XA slot sslot; SK += sb + W*XA ----------------
// grid (8, 4, B)
__global__ __launch_bounds__(256, 4) void k_skip(
    const u16* __restrict__ XA, float* __restrict__ SK,
    const float* __restrict__ SWTl, const float* __restrict__ sb, int sslot) {
  __shared__ __align__(16) float wsm[4096];  // [c][o64]
  __shared__ __align__(16) float xsm[1024];  // [cc16][n64]
  const int tx = threadIdx.x, ty = threadIdx.y;
  const int tid = ty * 16 + tx;
  const int n0 = blockIdx.x * 64, o0 = blockIdx.y * 64, b = blockIdx.z;
  for (int i = tid; i < 4096; i += 256) {
    int oo = i & 63, c = i >> 6;
    wsm[i] = SWTl[c * 256 + o0 + oo];
  }
  v4 acc[4] = {};
  const size_t xbase = (size_t)sslot * SLOT + (size_t)b * C * NPT;
  for (int c0 = 0; c0 < 64; c0 += 16) {
    __syncthreads();
    for (int i = tid; i < 1024; i += 256) {
      int nn = i & 63, cc = i >> 6;
      int n = n0 + nn;
      xsm[i] = (n < NPT) ? bf2f(XA[xbase + (size_t)(c0 + cc) * NPT + n]) : 0.f;
    }
    __syncthreads();
#pragma unroll
    for (int cc = 0; cc < 16; ++cc) {
      v4 xv = *(const v4*)&xsm[cc * 64 + tx * 4];
      v4 wv = *(const v4*)&wsm[(c0 + cc) * 64 + ty * 4];
#pragma unroll
      for (int r = 0; r < 4; ++r) acc[r] += wv[r] * xv;
    }
  }
#pragma unroll
  for (int r = 0; r < 4; ++r) {
    int o = o0 + ty * 4 + r;
    float bb = sb[o];
    size_t ob = (size_t)o * (B * NPT) + (size_t)b * NPT + n0 + tx * 4;
#pragma unroll
    for (int q = 0; q < 4; ++q) {
      int n = n0 + tx * 4 + q;
      if (n < NPT) SK[ob + q] += acc[r][q] + bb;
    }
  }
}

// ---------------- diffusion + mix + residual: grid (8, nT, B) ----------------
// reads XA slot blockIdx.y, residual XIN slot (t+d), writes XOUT slot t (t = t0+blockIdx.y)
// For the slice-serial fallback, XOUT == XIN (in-place is race-free per-slice).
__global__ __launch_bounds__(256, 4) void k_diffmix(
    const u16* __restrict__ XA, const u16* __restrict__ XIN, u16* __restrict__ XOUT,
    const float* __restrict__ Sup, const float* __restrict__ GWTl,
    const float* __restrict__ gb, int t0, int d) {
  __shared__ __align__(16) float sm[8704];  // 34,816 B
  const int tx = threadIdx.x, ty = threadIdx.y;
  const int tid = ty * 16 + tx;
  const int n0 = blockIdx.x * 64, ts = blockIdx.y, b = blockIdx.z;
  const int t = t0 + ts;
  float* xs = sm;          // [25][68] (m, c)
  float* s0 = sm + 1700;   // [25][68] (m, n)
  float* s1 = sm + 3400;
  v4 h0[4] = {}, h1[4] = {};
  const size_t xabase = (size_t)ts * SLOT + (size_t)b * C * NPT;
  for (int m0 = 0; m0 < NPT; m0 += 25) {
    __syncthreads();
    for (int i = tid; i < 1600; i += 256) {
      int mm = i % 25, cc = i / 25;
      xs[mm * 68 + cc] = bf2f(XA[xabase + (size_t)cc * NPT + m0 + mm]);
    }
    for (int i = tid; i < 1600; i += 256) {
      int mm = i % 25, nn = i / 25;
      int n = n0 + nn;
      float a0 = 0.f, a1 = 0.f;
      if (n < NPT) {
        a0 = Sup[(size_t)n * NPT + m0 + mm];
        a1 = Sup[(size_t)(NPT + n) * NPT + m0 + mm];
      }
      s0[mm * 68 + nn] = a0;
      s1[mm * 68 + nn] = a1;
    }
    __syncthreads();
#pragma unroll 5
    for (int mm = 0; mm < 25; ++mm) {
      v4 xv = *(const v4*)&xs[mm * 68 + ty * 4];
      v4 a0 = *(const v4*)&s0[mm * 68 + tx * 4];
      v4 a1 = *(const v4*)&s1[mm * 68 + tx * 4];
#pragma unroll
      for (int r = 0; r < 4; ++r) {
        h0[r] += xv[r] * a0;
        h1[r] += xv[r] * a1;
      }
    }
  }
  // phase B: mix over c (weights via L1 broadcast reads, no LDS staging)
  __syncthreads();
  float* hs0 = sm;          // [64][68]
  float* hs1 = sm + 4352;
#pragma unroll
  for (int r = 0; r < 4; ++r)
#pragma unroll
    for (int q = 0; q < 4; ++q) {
      hs0[(ty * 4 + r) * 68 + tx * 4 + q] = h0[r][q];
      hs1[(ty * 4 + r) * 68 + tx * 4 + q] = h1[r][q];
    }
  __syncthreads();
  v4 acc[4] = {};
#pragma unroll 4
  for (int c = 0; c < 64; ++c) {
    v4 hv0 = *(const v4*)&hs0[c * 68 + tx * 4];
    v4 hv1 = *(const v4*)&hs1[c * 68 + tx * 4];
    v4 w0 = *(const v4*)&GWTl[c * 64 + ty * 4];
    v4 w1 = *(const v4*)&GWTl[(64 + c) * 64 + ty * 4];
#pragma unroll
    for (int r = 0; r < 4; ++r) acc[r] += w0[r] * hv0 + w1[r] * hv1;
  }
  const int n = n0 + tx * 4;
  if (n < NPT) {
#pragma unroll
    for (int r = 0; r < 4; ++r) {
      int o = ty * 4 + r;
      float bias = gb[o];
      size_t orow = (size_t)t * SLOT + ((size_t)b * C + o) * NPT + n;
      size_t rrow = (size_t)(t + d) * SLOT + ((size_t)b * C + o) * NPT + n;
      ushort4 rv = *(const ushort4*)&XIN[rrow];
      ushort4 ov;
      ov.x = f2bf(acc[r][0] + bias + bf2f(rv.x));
      ov.y = f2bf(acc[r][1] + bias + bf2f(rv.y));
      ov.z = f2bf(acc[r][2] + bias + bf2f(rv.z));
      ov.w = f2bf(acc[r][3] + bias + bf2f(rv.w));
      *(ushort4*)&XOUT[orow] = ov;
    }
  }
}

__global__ void k_zero(double* __restrict__ p) {
  if (threadIdx.x < 128) p[threadIdx.x] = 0.0;
}

__global__ void k_zero_sk(float* __restrict__ p) {
  size_t i = ((size_t)blockIdx.x * 256 + threadIdx.x) * 4;
  v4 z = {};
  *(v4*)&p[i] = z;
}

// ---------------- BN pass 1: per-channel sum (f64) over slots 0..Tp-1 ----------------
__global__ void k_bnsum(const u16* __restrict__ X, double* __restrict__ st, int Tp) {
  int c = blockIdx.y;
  int per = Tp * B * NPT;
  double s = 0.0;
  for (int p = blockIdx.x * 256 + threadIdx.x; p < per; p += 8 * 256) {
    int t = p / (B * NPT);
    int r = p - t * (B * NPT);
    int b = r / NPT, n = r - b * NPT;
    s += (double)bf2f(X[(size_t)t * SLOT + ((size_t)b * C + c) * NPT + n]);
  }
  for (int off = 32; off; off >>= 1) s += __shfl_down(s, off, 64);
  if ((threadIdx.x & 63) == 0) atomicAdd(&st[c], s);
}

// ---------------- BN pass 2: per-channel sum of (x-mean)^2 ----------------
__global__ void k_bnvar(const u16* __restrict__ X, double* __restrict__ st, int Tp) {
  int c = blockIdx.y;
  int per = Tp * B * NPT;
  double mean = st[c] / (double)per;
  double s = 0.0;
  for (int p = blockIdx.x * 256 + threadIdx.x; p < per; p += 8 * 256) {
    int t = p / (B * NPT);
    int r = p - t * (B * NPT);
    int b = r / NPT, n = r - b * NPT;
    double d2 = (double)bf2f(X[(size_t)t * SLOT + ((size_t)b * C + c) * NPT + n]) - mean;
    s += d2 * d2;
  }
  for (int off = 32; off; off >>= 1) s += __shfl_down(s, off, 64);
  if ((threadIdx.x & 63) == 0) atomicAdd(&st[C + c], s);
}

// ---------------- BN apply in place on slots 0..Tp-1 ----------------
__global__ void k_bnapply(u16* __restrict__ X, const double* __restrict__ st,
                          const float* __restrict__ gamma, const float* __restrict__ beta,
                          int Tp) {
  size_t g = ((size_t)blockIdx.x * 256 + threadIdx.x) * 4;
  size_t r = g % SLOT;
  int c = (int)((r / NPT) % C);
  double cnt = (double)Tp * (double)(B * NPT);
  float mean = (float)(st[c] / cnt);
  float var = (float)(st[C + c] / cnt);
  float scl = gamma[c] * rsqrtf(var + 1e-5f);
  float sh = beta[c];
  ushort4 u = *(const ushort4*)&X[g];
  ushort4 o;
  o.x = f2bf((bf2f(u.x) - mean) * scl + sh);
  o.y = f2bf((bf2f(u.y) - mean) * scl + sh);
  o.z = f2bf((bf2f(u.z) - mean) * scl + sh);
  o.w = f2bf((bf2f(u.w) - mean) * scl + sh);
  *(ushort4*)&X[g] = o;
}

// ---------------- head 1: H1[e][p] = relu(b1 + W1 * relu(SK)) (bf16 out) ----------------
__global__ __launch_bounds__(256, 4) void k_out1(const float* __restrict__ SK,
                                                 const float* __restrict__ W1T,
                                                 const float* __restrict__ b1,
                                                 u16* __restrict__ H1) {
  __shared__ __align__(16) float ssm[32 * 64];
  __shared__ __align__(16) float wsm[32 * 64];
  const int tx = threadIdx.x, ty = threadIdx.y;
  const int tid = ty * 16 + tx;
  const int p0 = blockIdx.x * 64, e0 = blockIdx.y * 64;
  v4 acc[4] = {};
  for (int o0 = 0; o0 < SC; o0 += 32) {
    __syncthreads();
    for (int i = tid; i < 2048; i += 256) {
      int pp = i & 63, kk = i >> 6;
      ssm[i] = fmaxf(SK[(size_t)(o0 + kk) * (B * NPT) + p0 + pp], 0.f);
      wsm[i] = W1T[(size_t)(o0 + kk) * 512 + e0 + pp];
    }
    __syncthreads();
#pragma unroll
    for (int kk = 0; kk < 32; ++kk) {
      v4 sv = *(const v4*)&ssm[kk * 64 + tx * 4];
      v4 wv = *(const v4*)&wsm[kk * 64 + ty * 4];
#pragma unroll
      for (int r = 0; r < 4; ++r) acc[r] += wv[r] * sv;
    }
  }
#pragma unroll
  for (int r = 0; r < 4; ++r) {
    int e = e0 + ty * 4 + r;
    float bb = b1[e];
    size_t ob = (size_t)e * (B * NPT) + p0 + tx * 4;
#pragma unroll
    for (int q = 0; q < 4; ++q) H1[ob + q] = f2bf(fmaxf(acc[r][q] + bb, 0.f));
  }
}

// ---------------- head 2 ----------------
__global__ __launch_bounds__(256) void k_out2(const u16* __restrict__ H1,
                                              const float* __restrict__ W2,
                                              const float* __restrict__ b2,
                                              float* __restrict__ out) {
  int idx = blockIdx.x * 256 + threadIdx.x;
  if (idx >= B * PR * NPT) return;
  int n = idx % NPT;
  int p12 = (idx / NPT) % PR;
  int b = idx / (NPT * PR);
  size_t p = (size_t)b * NPT + n;
  const float* w = W2 + p12 * EC;
  float acc = b2[p12];
  for (int e = 0; e < EC; e += 4) {
    acc += w[e] * bf2f(H1[(size_t)e * (B * NPT) + p])
         + w[e + 1] * bf2f(H1[(size_t)(e + 1) * (B * NPT) + p])
         + w[e + 2] * bf2f(H1[(size_t)(e + 2) * (B * NPT) + p])
         + w[e + 3] * bf2f(H1[(size_t)(e + 3) * (B * NPT) + p]);
  }
  out[idx] = acc;
}

}  // namespace

extern "C" void kernel_launch(void* const* d_in, const int* in_sizes, int n_in,
                              void* d_out, int out_size, void* d_ws, size_t ws_size,
                              hipStream_t stream) {
  const float* inputs  = (const float*)d_in[0];
  const float* sup     = (const float*)d_in[1];
  const float* enter_w = (const float*)d_in[2];
  const float* enter_b = (const float*)d_in[3];
  const float* filt_w  = (const float*)d_in[4];
  const float* filt_b  = (const float*)d_in[5];
  const float* gate_w  = (const float*)d_in[6];
  const float* gate_b  = (const float*)d_in[7];
  const float* gconv_w = (const float*)d_in[8];
  const float* gconv_b = (const float*)d_in[9];
  const float* skip_w  = (const float*)d_in[10];
  const float* skip_b  = (const float*)d_in[11];
  const float* bn_g    = (const float*)d_in[12];
  const float* bn_b    = (const float*)d_in[13];
  const float* o1w     = (const float*)d_in[14];
  const float* o1b     = (const float*)d_in[15];
  const float* o2w     = (const float*)d_in[16];
  const float* o2b     = (const float*)d_in[17];
  (void)in_sizes; (void)n_in; (void)out_size;

  if (ws_size < WS_LEG) {
    k_debug_ws<<<1500, 256, 0, stream>>>((float*)d_out, (float)(ws_size >> 20));
    return;
  }
  const bool fast = ws_size >= WS_FAST;

  char* base = (char*)d_ws;
  u16* bufA = (u16*)base;                      // 13 slots
  u16* bufB;                                   // 12 slots (fast only)
  u16* XA;                                     // 12 slots (fast) / 1 slot (legacy)
  float* SK;
  if (fast) {
    bufB = (u16*)(base + SZ_A);
    XA   = (u16*)(base + SZ_A + SZ_Bb);
    SK   = (float*)(base + SZ_A + SZ_Bb + SZ_XA12);
  } else {
    bufB = bufA;  // unused distinctness; legacy is in-place
    XA   = (u16*)(base + SZ_A);
    SK   = (float*)(base + SZ_A + SZ_XA1);
  }
  double* ST = (double*)((char*)SK + SZ_SK);
  float* W   = (float*)((char*)ST + SZ_ST);
  float* WF  = W;
  float* WG  = W + 65536;
  float* SWT = W + 131072;
  float* GWT = W + 262144;
  float* W1T = W + 327680;

  k_prep<<<1792, 256, 0, stream>>>(filt_w, gate_w, skip_w, gconv_w, o1w,
                                   WF, WG, SWT, GWT, W1T);
  k_enter<<<(int)((13 * SLOT) / 256), 256, 0, stream>>>(inputs, enter_w, enter_b, bufA);
  k_zero_sk<<<8000, 256, 0, stream>>>(SK);

  static const int dils[8] = {1, 2, 1, 2, 1, 2, 1, 2};
  u16* bufs[2] = {bufA, bufB};
  int T = T0;
  for (int l = 0; l < 8; ++l) {
    const int d = dils[l];
    const int Tp = T - d;
    u16* XIN  = fast ? bufs[l & 1] : bufA;
    u16* XOUT = fast ? bufs[(l + 1) & 1] : bufA;
    if (fast) {
      k_gatedconv<<<dim3(8, Tp, B), dim3(16, 16), 0, stream>>>(
          XIN, XA, WF + l * 8192, filt_b + l * 64, WG + l * 8192, gate_b + l * 64, 0, d);
      k_skip<<<dim3(8, 4, B), dim3(16, 16), 0, stream>>>(
          XA, SK, SWT + l * 16384, skip_b + l * 256, Tp - 1);
      k_diffmix<<<dim3(8, Tp, B), dim3(16, 16), 0, stream>>>(
          XA, XIN, XOUT, sup, GWT + l * 8192, gconv_b + l * 64, 0, d);
    } else {
      for (int t = 0; t < Tp; ++t) {
        k_gatedconv<<<dim3(8, 1, B), dim3(16, 16), 0, stream>>>(
            XIN, XA, WF + l * 8192, filt_b + l * 64, WG + l * 8192, gate_b + l * 64, t, d);
        if (t == Tp - 1)
          k_skip<<<dim3(8, 4, B), dim3(16, 16), 0, stream>>>(
              XA, SK, SWT + l * 16384, skip_b + l * 256, 0);
        k_diffmix<<<dim3(8, 1, B), dim3(16, 16), 0, stream>>>(
            XA, XIN, XOUT, sup, GWT + l * 8192, gconv_b + l * 64, t, d);
      }
    }
    k_zero<<<1, 128, 0, stream>>>(ST);
    k_bnsum<<<dim3(8, C), 256, 0, stream>>>(XOUT, ST, Tp);
    k_bnvar<<<dim3(8, C), 256, 0, stream>>>(XOUT, ST, Tp);
    k_bnapply<<<Tp * 2000, 256, 0, stream>>>(XOUT, ST, bn_g + l * 64, bn_b + l * 64, Tp);
    T = Tp;
  }

  u16* H1 = fast ? XA : bufA;  // overlay: unused after the loop
  k_out1<<<dim3(500, 8), dim3(16, 16), 0, stream>>>(SK, W1T, o1b, H1);
  k_out2<<<1500, 256, 0, stream>>>(H1, o2w, o2b, (float*)d_out);
}

// Round 6
// 6570.882 us; speedup vs baseline: 2.1821x; 2.1821x over previous
//
#include <hip/hip_runtime.h>

typedef float v4 __attribute__((ext_vector_type(4)));
typedef unsigned short u16;
typedef unsigned int u32;

#define DEVI __device__ __forceinline__

namespace {

constexpr int B = 64, C = 64, NPT = 500, T0 = 13, SC = 256, EC = 512, PR = 12;
constexpr size_t SLOT = (size_t)B * C * NPT;  // 2,048,000 elems per time slice

// sizes (bytes)
constexpr size_t SZ_A    = 13 * SLOT * 2;            // x ping (bf16)
constexpr size_t SZ_Bb   = 12 * SLOT * 2;            // x pong (bf16)
constexpr size_t SZ_XA12 = 12 * SLOT * 2;            // gated (bf16, batched)
constexpr size_t SZ_XA1  = SLOT * 2;                 // gated (bf16, 1 slot)
constexpr size_t SZ_SK   = (size_t)SC * B * NPT * 4; // skip acc f32
constexpr size_t SZ_ST   = 1024;                     // f64[128]
constexpr size_t SZ_W    = (size_t)(65536 + 65536 + 131072 + 65536 + 131072) * 4;

constexpr size_t WS_FAST = SZ_A + SZ_Bb + SZ_XA12 + SZ_SK + SZ_ST + SZ_W; // 186,156,032
constexpr size_t WS_LEG  = SZ_A + SZ_XA1 + SZ_SK + SZ_ST + SZ_W;          //  91,948,032

DEVI float sigm(float x) { return 1.f / (1.f + expf(-x)); }
DEVI float bf2f(u16 u) { u32 x = ((u32)u) << 16; float f; __builtin_memcpy(&f, &x, 4); return f; }
DEVI u16 f2bf(float f) { u32 x; __builtin_memcpy(&x, &f, 4); return (u16)((x + 0x7FFF + ((x >> 16) & 1)) >> 16); }

// ---------------- debug: report ws_size (MB) through the output ----------------
__global__ void k_debug_ws(float* __restrict__ out, float val) {
  int i = blockIdx.x * 256 + threadIdx.x;
  if (i < B * PR * NPT) out[i] = val;
}

// ---------------- weight repack ----------------
__global__ void k_prep(const float* __restrict__ fw, const float* __restrict__ gw,
                       const float* __restrict__ sw, const float* __restrict__ gcw,
                       const float* __restrict__ o1w,
                       float* __restrict__ WF, float* __restrict__ WG,
                       float* __restrict__ SWT, float* __restrict__ GWT,
                       float* __restrict__ W1T) {
  int i = blockIdx.x * 256 + threadIdx.x;
  if (i < 65536) {  // [l][tap][c][cp] <- fw[((l*64+cp)*64+c)*2+tap]
    int cp = i & 63, c = (i >> 6) & 63, tap = (i >> 12) & 1, l = i >> 13;
    int g = ((l * 64 + cp) * 64 + c) * 2 + tap;
    WF[i] = fw[g];
    WG[i] = gw[g];
  }
  int j = i - 131072;
  if (j >= 0 && j < 131072) {  // [l][c][o] <- sw[(l*256+o)*64+c]
    int o = j & 255, cl = (j >> 8) & 63, l = j >> 14;
    SWT[j] = sw[(l * 256 + o) * 64 + cl];
  }
  int k2 = i - 262144;
  if (k2 >= 0 && k2 < 65536) {  // [l][kc][o] <- gcw[(l*64+o)*128+kc]
    int o = k2 & 63, kc = (k2 >> 6) & 127, l = k2 >> 13;
    GWT[k2] = gcw[(l * 64 + o) * 128 + kc];
  }
  int m = i - 327680;
  if (m >= 0 && m < 131072) {  // [o][e] <- o1w[e*256+o]
    int e = m & 511, o = m >> 9;
    W1T[m] = o1w[e * 256 + o];
  }
}

// ---------------- enter: [B,12,N,2] -> Xbf[t][b][c][n], t=0 is left-pad ----------------
__global__ void k_enter(const float* __restrict__ in, const float* __restrict__ ew,
                        const float* __restrict__ eb, u16* __restrict__ X) {
  size_t idx = (size_t)blockIdx.x * 256 + threadIdx.x;
  if (idx >= 13 * SLOT) return;
  int t = (int)(idx / SLOT);
  size_t r = idx % SLOT;
  int n = (int)(r % NPT);
  int c = (int)((r / NPT) % C);
  int b = (int)(r / ((size_t)NPT * C));
  float v = eb[c];
  if (t > 0) {
    const float* ip = in + (((size_t)b * 12 + (t - 1)) * NPT + n) * 2;
    v += ew[c * 2] * ip[0] + ew[c * 2 + 1] * ip[1];
  }
  X[idx] = f2bf(v);
}

// ---------------- gated conv: grid (8, nT, B); slice t = t0 + blockIdx.y ----------------
__global__ __launch_bounds__(256) void k_gatedconv(
    const u16* __restrict__ X, u16* __restrict__ XA,
    const float* __restrict__ WFl, const float* __restrict__ bf,
    const float* __restrict__ WGl, const float* __restrict__ bg,
    int t0, int d) {
  __shared__ __align__(16) float wfs[8192];  // [tap][c][cp64] full
  __shared__ __align__(16) float wgs[8192];
  __shared__ __align__(16) float xs[2048];   // [tap][cc16][n64]
  const int tx = threadIdx.x, ty = threadIdx.y;
  const int tid = ty * 16 + tx;
  const int n0 = blockIdx.x * 64;
  const int ts = blockIdx.y;
  const int b = blockIdx.z;
  const int t = t0 + ts;
  for (int i = tid; i < 8192; i += 256) {
    wfs[i] = WFl[i];
    wgs[i] = WGl[i];
  }
  v4 f[4] = {}, g[4] = {};
  for (int c0 = 0; c0 < 64; c0 += 16) {
    __syncthreads();
    for (int i2 = tid; i2 < 512; i2 += 256) {  // 512 ushort4 slots
      int nv = i2 & 15, cc = (i2 >> 4) & 15, tap = i2 >> 8;
      int n = n0 + nv * 4;
      const u16* src = &X[(size_t)(t + tap * d) * SLOT + ((size_t)b * C + c0 + cc) * NPT + n];
      float* dst = &xs[tap * 1024 + cc * 64 + nv * 4];
      if (n + 3 < NPT) {
        ushort4 u = *(const ushort4*)src;
        dst[0] = bf2f(u.x); dst[1] = bf2f(u.y); dst[2] = bf2f(u.z); dst[3] = bf2f(u.w);
      } else {
        for (int q = 0; q < 4; ++q) dst[q] = (n + q < NPT) ? bf2f(src[q]) : 0.f;
      }
    }
    __syncthreads();
#pragma unroll
    for (int cc = 0; cc < 16; ++cc) {
      v4 xv0 = *(const v4*)&xs[cc * 64 + tx * 4];
      v4 xv1 = *(const v4*)&xs[1024 + cc * 64 + tx * 4];
      int c = c0 + cc;
      v4 wf0 = *(const v4*)&wfs[c * 64 + ty * 4];
      v4 wf1 = *(const v4*)&wfs[4096 + c * 64 + ty * 4];
      v4 wg0 = *(const v4*)&wgs[c * 64 + ty * 4];
      v4 wg1 = *(const v4*)&wgs[4096 + c * 64 + ty * 4];
#pragma unroll
      for (int r = 0; r < 4; ++r) {
        f[r] += wf0[r] * xv0 + wf1[r] * xv1;
        g[r] += wg0[r] * xv0 + wg1[r] * xv1;
      }
    }
  }
  const int cp = ty * 4;
  const int n = n0 + tx * 4;
  if (n < NPT) {
#pragma unroll
    for (int r = 0; r < 4; ++r) {
      float fb = bf[cp + r], gb2 = bg[cp + r];
      size_t ob = (size_t)ts * SLOT + ((size_t)b * C + cp + r) * NPT + n;
      ushort4 ov;
      ov.x = f2bf(tanhf(f[r][0] + fb) * sigm(g[r][0] + gb2));
      ov.y = f2bf(tanhf(f[r][1] + fb) * sigm(g[r][1] + gb2));
      ov.z = f2bf(tanhf(f[r][2] + fb) * sigm(g[r][2] + gb2));
      ov.w = f2bf(tanhf(f[r][3] + fb) * sigm(g[r][3] + gb2));
      *(ushort4*)&XA[ob] = ov;
    }
  }
}

// ---------------- skip GEMM on XA slot sslot; SK += sb + W*XA ; grid (8,4,B) ----------------
__global__ __launch_bounds__(256) void k_skip(
    const u16* __restrict__ XA, float* __restrict__ SK,
    const float* __restrict__ SWTl, const float* __restrict__ sb, int sslot) {
  __shared__ __align__(16) float wsm[4096];  // [c][o64]
  __shared__ __align__(16) float xsm[1024];  // [cc16][n64]
  const int tx = threadIdx.x, ty = threadIdx.y;
  const int tid = ty * 16 + tx;
  const int n0 = blockIdx.x * 64, o0 = blockIdx.y * 64, b = blockIdx.z;
  for (int i = tid; i < 1024; i += 256) {  // v4 weight stage
    int c = i >> 4, ov = i & 15;
    *(v4*)&wsm[c * 64 + ov * 4] = *(const v4*)&SWTl[c * 256 + o0 + ov * 4];
  }
  v4 acc[4] = {};
  const size_t xbase = (size_t)sslot * SLOT + (size_t)b * C * NPT;
  for (int c0 = 0; c0 < 64; c0 += 16) {
    __syncthreads();
    {
      int nv = tid & 15, cc = tid >> 4;
      int n = n0 + nv * 4;
      const u16* src = &XA[xbase + (size_t)(c0 + cc) * NPT + n];
      float* dst = &xsm[cc * 64 + nv * 4];
      if (n + 3 < NPT) {
        ushort4 u = *(const ushort4*)src;
        dst[0] = bf2f(u.x); dst[1] = bf2f(u.y); dst[2] = bf2f(u.z); dst[3] = bf2f(u.w);
      } else {
        for (int q = 0; q < 4; ++q) dst[q] = (n + q < NPT) ? bf2f(src[q]) : 0.f;
      }
    }
    __syncthreads();
#pragma unroll
    for (int cc = 0; cc < 16; ++cc) {
      v4 xv = *(const v4*)&xsm[cc * 64 + tx * 4];
      v4 wv = *(const v4*)&wsm[(c0 + cc) * 64 + ty * 4];
#pragma unroll
      for (int r = 0; r < 4; ++r) acc[r] += wv[r] * xv;
    }
  }
#pragma unroll
  for (int r = 0; r < 4; ++r) {
    int o = o0 + ty * 4 + r;
    float bb = sb[o];
    size_t ob = (size_t)o * (B * NPT) + (size_t)b * NPT + n0 + tx * 4;
#pragma unroll
    for (int q = 0; q < 4; ++q) {
      int n = n0 + tx * 4 + q;
      if (n < NPT) SK[ob + q] += acc[r][q] + bb;
    }
  }
}

// ---------------- diffusion + mix + residual: grid (8, nT, B) ----------------
__global__ __launch_bounds__(256, 4) void k_diffmix(
    const u16* __restrict__ XA, const u16* __restrict__ XIN, u16* __restrict__ XOUT,
    const float* __restrict__ Sup, const float* __restrict__ GWTl,
    const float* __restrict__ gb, int t0, int d) {
  __shared__ __align__(16) float sm[8704];  // 34,816 B
  const int tx = threadIdx.x, ty = threadIdx.y;
  const int tid = ty * 16 + tx;
  const int n0 = blockIdx.x * 64, ts = blockIdx.y, b = blockIdx.z;
  const int t = t0 + ts;
  float* xs = sm;          // [25][68] (m, c)
  float* s0 = sm + 1700;   // [25][68] (m, n)
  float* s1 = sm + 3400;
  v4 h0[4] = {}, h1[4] = {};
  const size_t xabase = (size_t)ts * SLOT + (size_t)b * C * NPT;
  for (int m0 = 0; m0 < NPT; m0 += 25) {
    __syncthreads();
    for (int i = tid; i < 1600; i += 256) {
      int mm = i % 25, cc = i / 25;
      xs[mm * 68 + cc] = bf2f(XA[xabase + (size_t)cc * NPT + m0 + mm]);
    }
    for (int i = tid; i < 1600; i += 256) {
      int mm = i % 25, nn = i / 25;
      int n = n0 + nn;
      float a0 = 0.f, a1 = 0.f;
      if (n < NPT) {
        a0 = Sup[(size_t)n * NPT + m0 + mm];
        a1 = Sup[(size_t)(NPT + n) * NPT + m0 + mm];
      }
      s0[mm * 68 + nn] = a0;
      s1[mm * 68 + nn] = a1;
    }
    __syncthreads();
#pragma unroll 5
    for (int mm = 0; mm < 25; ++mm) {
      v4 xv = *(const v4*)&xs[mm * 68 + ty * 4];
      v4 a0 = *(const v4*)&s0[mm * 68 + tx * 4];
      v4 a1 = *(const v4*)&s1[mm * 68 + tx * 4];
#pragma unroll
      for (int r = 0; r < 4; ++r) {
        h0[r] += xv[r] * a0;
        h1[r] += xv[r] * a1;
      }
    }
  }
  // phase B: mix over c (weights via L1 broadcast reads)
  __syncthreads();
  float* hs0 = sm;          // [64][68]
  float* hs1 = sm + 4352;
#pragma unroll
  for (int r = 0; r < 4; ++r)
#pragma unroll
    for (int q = 0; q < 4; ++q) {
      hs0[(ty * 4 + r) * 68 + tx * 4 + q] = h0[r][q];
      hs1[(ty * 4 + r) * 68 + tx * 4 + q] = h1[r][q];
    }
  __syncthreads();
  v4 acc[4] = {};
#pragma unroll 4
  for (int c = 0; c < 64; ++c) {
    v4 hv0 = *(const v4*)&hs0[c * 68 + tx * 4];
    v4 hv1 = *(const v4*)&hs1[c * 68 + tx * 4];
    v4 w0 = *(const v4*)&GWTl[c * 64 + ty * 4];
    v4 w1 = *(const v4*)&GWTl[(64 + c) * 64 + ty * 4];
#pragma unroll
    for (int r = 0; r < 4; ++r) acc[r] += w0[r] * hv0 + w1[r] * hv1;
  }
  const int n = n0 + tx * 4;
  if (n < NPT) {
#pragma unroll
    for (int r = 0; r < 4; ++r) {
      int o = ty * 4 + r;
      float bias = gb[o];
      size_t orow = (size_t)t * SLOT + ((size_t)b * C + o) * NPT + n;
      size_t rrow = (size_t)(t + d) * SLOT + ((size_t)b * C + o) * NPT + n;
      ushort4 rv = *(const ushort4*)&XIN[rrow];
      ushort4 ov;
      ov.x = f2bf(acc[r][0] + bias + bf2f(rv.x));
      ov.y = f2bf(acc[r][1] + bias + bf2f(rv.y));
      ov.z = f2bf(acc[r][2] + bias + bf2f(rv.z));
      ov.w = f2bf(acc[r][3] + bias + bf2f(rv.w));
      *(ushort4*)&XOUT[orow] = ov;
    }
  }
}

__global__ void k_zero(double* __restrict__ p) {
  if (threadIdx.x < 128) p[threadIdx.x] = 0.0;
}

__global__ void k_zero_sk(float* __restrict__ p) {
  size_t i = ((size_t)blockIdx.x * 256 + threadIdx.x) * 4;
  v4 z = {};
  *(v4*)&p[i] = z;
}

// ---------------- BN single-pass stats: f64 sum & sumsq per channel ----------------
__global__ void k_bnstats(const u16* __restrict__ X, double* __restrict__ st, int Tp) {
  int c = blockIdx.y;
  int perv = Tp * B * 125;  // ushort4 slots
  double s = 0.0, ss = 0.0;
  for (int p = blockIdx.x * 256 + threadIdx.x; p < perv; p += 8 * 256) {
    int t = p / (B * 125);
    int r = p - t * (B * 125);
    int b = r / 125, nv = r - b * 125;
    ushort4 u = *(const ushort4*)&X[(size_t)t * SLOT + ((size_t)b * C + c) * NPT + nv * 4];
    double x0 = (double)bf2f(u.x), x1 = (double)bf2f(u.y);
    double x2 = (double)bf2f(u.z), x3 = (double)bf2f(u.w);
    s += (x0 + x1) + (x2 + x3);
    ss += (x0 * x0 + x1 * x1) + (x2 * x2 + x3 * x3);
  }
  for (int off = 32; off; off >>= 1) {
    s += __shfl_down(s, off, 64);
    ss += __shfl_down(ss, off, 64);
  }
  if ((threadIdx.x & 63) == 0) {
    atomicAdd(&st[c], s);
    atomicAdd(&st[C + c], ss);
  }
}

// ---------------- BN apply in place on slots 0..Tp-1 ----------------
__global__ void k_bnapply(u16* __restrict__ X, const double* __restrict__ st,
                          const float* __restrict__ gamma, const float* __restrict__ beta,
                          int Tp) {
  size_t g = ((size_t)blockIdx.x * 256 + threadIdx.x) * 4;
  size_t r = g % SLOT;
  int c = (int)((r / NPT) % C);
  double cnt = (double)Tp * (double)(B * NPT);
  double m = st[c] / cnt;
  double v = st[C + c] / cnt - m * m;  // safe in f64
  float mean = (float)m;
  float scl = gamma[c] * rsqrtf((float)v + 1e-5f);
  float sh = beta[c];
  ushort4 u = *(const ushort4*)&X[g];
  ushort4 o;
  o.x = f2bf((bf2f(u.x) - mean) * scl + sh);
  o.y = f2bf((bf2f(u.y) - mean) * scl + sh);
  o.z = f2bf((bf2f(u.z) - mean) * scl + sh);
  o.w = f2bf((bf2f(u.w) - mean) * scl + sh);
  *(ushort4*)&X[g] = o;
}

// ---------------- head 1: H1[e][p] = relu(b1 + W1 * relu(SK)) (bf16 out) ----------------
__global__ __launch_bounds__(256) void k_out1(const float* __restrict__ SK,
                                              const float* __restrict__ W1T,
                                              const float* __restrict__ b1,
                                              u16* __restrict__ H1) {
  __shared__ __align__(16) float ssm[32 * 64];
  __shared__ __align__(16) float wsm[32 * 64];
  const int tx = threadIdx.x, ty = threadIdx.y;
  const int tid = ty * 16 + tx;
  const int p0 = blockIdx.x * 64, e0 = blockIdx.y * 64;
  v4 acc[4] = {};
  for (int o0 = 0; o0 < SC; o0 += 32) {
    __syncthreads();
    for (int i = tid; i < 2048; i += 256) {
      int pp = i & 63, kk = i >> 6;
      ssm[i] = fmaxf(SK[(size_t)(o0 + kk) * (B * NPT) + p0 + pp], 0.f);
      wsm[i] = W1T[(size_t)(o0 + kk) * 512 + e0 + pp];
    }
    __syncthreads();
#pragma unroll
    for (int kk = 0; kk < 32; ++kk) {
      v4 sv = *(const v4*)&ssm[kk * 64 + tx * 4];
      v4 wv = *(const v4*)&wsm[kk * 64 + ty * 4];
#pragma unroll
      for (int r = 0; r < 4; ++r) acc[r] += wv[r] * sv;
    }
  }
#pragma unroll
  for (int r = 0; r < 4; ++r) {
    int e = e0 + ty * 4 + r;
    float bb = b1[e];
    size_t ob = (size_t)e * (B * NPT) + p0 + tx * 4;
#pragma unroll
    for (int q = 0; q < 4; ++q) H1[ob + q] = f2bf(fmaxf(acc[r][q] + bb, 0.f));
  }
}

// ---------------- head 2 ----------------
__global__ __launch_bounds__(256) void k_out2(const u16* __restrict__ H1,
                                              const float* __restrict__ W2,
                                              const float* __restrict__ b2,
                                              float* __restrict__ out) {
  int idx = blockIdx.x * 256 + threadIdx.x;
  if (idx >= B * PR * NPT) return;
  int n = idx % NPT;
  int p12 = (idx / NPT) % PR;
  int b = idx / (NPT * PR);
  size_t p = (size_t)b * NPT + n;
  const float* w = W2 + p12 * EC;
  float acc = b2[p12];
  for (int e = 0; e < EC; e += 4) {
    acc += w[e] * bf2f(H1[(size_t)e * (B * NPT) + p])
         + w[e + 1] * bf2f(H1[(size_t)(e + 1) * (B * NPT) + p])
         + w[e + 2] * bf2f(H1[(size_t)(e + 2) * (B * NPT) + p])
         + w[e + 3] * bf2f(H1[(size_t)(e + 3) * (B * NPT) + p]);
  }
  out[idx] = acc;
}

}  // namespace

extern "C" void kernel_launch(void* const* d_in, const int* in_sizes, int n_in,
                              void* d_out, int out_size, void* d_ws, size_t ws_size,
                              hipStream_t stream) {
  const float* inputs  = (const float*)d_in[0];
  const float* sup     = (const float*)d_in[1];
  const float* enter_w = (const float*)d_in[2];
  const float* enter_b = (const float*)d_in[3];
  const float* filt_w  = (const float*)d_in[4];
  const float* filt_b  = (const float*)d_in[5];
  const float* gate_w  = (const float*)d_in[6];
  const float* gate_b  = (const float*)d_in[7];
  const float* gconv_w = (const float*)d_in[8];
  const float* gconv_b = (const float*)d_in[9];
  const float* skip_w  = (const float*)d_in[10];
  const float* skip_b  = (const float*)d_in[11];
  const float* bn_g    = (const float*)d_in[12];
  const float* bn_b    = (const float*)d_in[13];
  const float* o1w     = (const float*)d_in[14];
  const float* o1b     = (const float*)d_in[15];
  const float* o2w     = (const float*)d_in[16];
  const float* o2b     = (const float*)d_in[17];
  (void)in_sizes; (void)n_in; (void)out_size;

  if (ws_size < WS_LEG) {
    k_debug_ws<<<1500, 256, 0, stream>>>((float*)d_out, (float)(ws_size >> 20));
    return;
  }
  const bool fast = ws_size >= WS_FAST;

  char* base = (char*)d_ws;
  u16* bufA = (u16*)base;                      // 13 slots
  u16* bufB;                                   // 12 slots (fast only)
  u16* XA;                                     // 12 slots (fast) / 1 slot (legacy)
  float* SK;
  if (fast) {
    bufB = (u16*)(base + SZ_A);
    XA   = (u16*)(base + SZ_A + SZ_Bb);
    SK   = (float*)(base + SZ_A + SZ_Bb + SZ_XA12);
  } else {
    bufB = bufA;
    XA   = (u16*)(base + SZ_A);
    SK   = (float*)(base + SZ_A + SZ_XA1);
  }
  double* ST = (double*)((char*)SK + SZ_SK);
  float* W   = (float*)((char*)ST + SZ_ST);
  float* WF  = W;
  float* WG  = W + 65536;
  float* SWT = W + 131072;
  float* GWT = W + 262144;
  float* W1T = W + 327680;

  k_prep<<<1792, 256, 0, stream>>>(filt_w, gate_w, skip_w, gconv_w, o1w,
                                   WF, WG, SWT, GWT, W1T);
  k_enter<<<(int)((13 * SLOT) / 256), 256, 0, stream>>>(inputs, enter_w, enter_b, bufA);
  k_zero_sk<<<8000, 256, 0, stream>>>(SK);

  static const int dils[8] = {1, 2, 1, 2, 1, 2, 1, 2};
  u16* bufs[2] = {bufA, bufB};
  int T = T0;
  for (int l = 0; l < 8; ++l) {
    const int d = dils[l];
    const int Tp = T - d;
    u16* XIN  = fast ? bufs[l & 1] : bufA;
    u16* XOUT = fast ? bufs[(l + 1) & 1] : bufA;
    if (fast) {
      k_gatedconv<<<dim3(8, Tp, B), dim3(16, 16), 0, stream>>>(
          XIN, XA, WF + l * 8192, filt_b + l * 64, WG + l * 8192, gate_b + l * 64, 0, d);
      k_skip<<<dim3(8, 4, B), dim3(16, 16), 0, stream>>>(
          XA, SK, SWT + l * 16384, skip_b + l * 256, Tp - 1);
      k_diffmix<<<dim3(8, Tp, B), dim3(16, 16), 0, stream>>>(
          XA, XIN, XOUT, sup, GWT + l * 8192, gconv_b + l * 64, 0, d);
    } else {
      for (int t = 0; t < Tp; ++t) {
        k_gatedconv<<<dim3(8, 1, B), dim3(16, 16), 0, stream>>>(
            XIN, XA, WF + l * 8192, filt_b + l * 64, WG + l * 8192, gate_b + l * 64, t, d);
        if (t == Tp - 1)
          k_skip<<<dim3(8, 4, B), dim3(16, 16), 0, stream>>>(
              XA, SK, SWT + l * 16384, skip_b + l * 256, 0);
        k_diffmix<<<dim3(8, 1, B), dim3(16, 16), 0, stream>>>(
            XA, XIN, XOUT, sup, GWT + l * 8192, gconv_b + l * 64, t, d);
      }
    }
    k_zero<<<1, 128, 0, stream>>>(ST);
    k_bnstats<<<dim3(8, C), 256, 0, stream>>>(XOUT, ST, Tp);
    k_bnapply<<<Tp * 2000, 256, 0, stream>>>(XOUT, ST, bn_g + l * 64, bn_b + l * 64, Tp);
    T = Tp;
  }

  u16* H1 = fast ? XA : bufA;  // overlay: unused after the loop
  k_out1<<<dim3(500, 8), dim3(16, 16), 0, stream>>>(SK, W1T, o1b, H1);
  k_out2<<<1500, 256, 0, stream>>>(H1, o2w, o2b, (float*)d_out);
}

// Round 7
// 3581.330 us; speedup vs baseline: 4.0036x; 1.8348x over previous
//
#include <hip/hip_runtime.h>

typedef float v4 __attribute__((ext_vector_type(4)));
typedef short bf8 __attribute__((ext_vector_type(8)));  // 8 bf16 in 4 VGPRs
typedef unsigned short u16;
typedef unsigned int u32;

#define DEVI __device__ __forceinline__

namespace {

constexpr int B = 64, C = 64, NPT = 500, NP = 512, T0 = 13, SC = 256, EC = 512, PR = 12;
constexpr size_t SLOTP = (size_t)B * C * NP;  // 2,097,152 elems per padded time slice

// byte offsets
constexpr size_t SZ_BUF  = 13 * SLOTP * 2;             // 54,525,952 per x buffer
constexpr size_t OFF_SK  = 2 * SZ_BUF;                 // f32 [256][B*NPT]
constexpr size_t SZ_SK   = (size_t)SC * B * NPT * 4;   // 32,768,000
constexpr size_t OFF_ST  = OFF_SK + SZ_SK;             // f64[128]
constexpr size_t OFF_WF  = OFF_ST + 1024;              // f32: WF 65536, WG 65536, SWT 131072, W1T 131072
constexpr size_t OFF_WMX = OFF_WF + (size_t)393216 * 4;   // u16 [8][64][128]
constexpr size_t OFF_SPD = OFF_WMX + (size_t)65536 * 2;   // u16 [2][512][512]
constexpr size_t WS_NEED = OFF_SPD + (size_t)524288 * 2;  // 144,573,440

DEVI float sigm(float x) { return 1.f / (1.f + expf(-x)); }
DEVI float bf2f(u16 u) { u32 x = ((u32)u) << 16; float f; __builtin_memcpy(&f, &x, 4); return f; }
DEVI u16 f2bf(float f) { u32 x; __builtin_memcpy(&x, &f, 4); return (u16)((x + 0x7FFF + ((x >> 16) & 1)) >> 16); }

__global__ void k_debug_ws(float* __restrict__ out, float val) {
  int i = blockIdx.x * 256 + threadIdx.x;
  if (i < B * PR * NPT) out[i] = val;
}

// ---------------- weight repack ----------------
__global__ void k_prep(const float* __restrict__ fw, const float* __restrict__ gw,
                       const float* __restrict__ sw, const float* __restrict__ gcw,
                       const float* __restrict__ o1w, const float* __restrict__ sup,
                       float* __restrict__ WF, float* __restrict__ WG,
                       float* __restrict__ SWT, float* __restrict__ W1T,
                       u16* __restrict__ WMX, u16* __restrict__ SPD) {
  int i = blockIdx.x * 256 + threadIdx.x;
  if (i < 65536) {  // [l][tap][c][cp] <- fw[((l*64+cp)*64+c)*2+tap]
    int cp = i & 63, c = (i >> 6) & 63, tap = (i >> 12) & 1, l = i >> 13;
    int g = ((l * 64 + cp) * 64 + c) * 2 + tap;
    WF[i] = fw[g];
    WG[i] = gw[g];
  }
  int j = i - 131072;
  if (j >= 0 && j < 131072) {  // [l][c][o] <- sw[(l*256+o)*64+c]
    int o = j & 255, cl = (j >> 8) & 63, l = j >> 14;
    SWT[j] = sw[(l * 256 + o) * 64 + cl];
  }
  int k2 = i - 262144;
  if (k2 >= 0 && k2 < 65536) {  // WMX[l][o][k128] = bf16(gcw) (identical index order)
    WMX[k2] = f2bf(gcw[k2]);
  }
  int m = i - 327680;
  if (m >= 0 && m < 131072) {  // [o][e] <- o1w[e*256+o]
    int e = m & 511, o = m >> 9;
    W1T[m] = o1w[e * 256 + o];
  }
  int sp = i - 458752;
  if (sp >= 0 && sp < 524288) {  // SPD[s][n512][m512] zero-padded bf16
    int mm = sp & 511, n = (sp >> 9) & 511, s = sp >> 18;
    float v = (n < NPT && mm < NPT) ? sup[(size_t)s * NPT * NPT + (size_t)n * NPT + mm] : 0.f;
    SPD[sp] = f2bf(v);
  }
}

// ---------------- enter: [B,12,N,2] -> Xbf[t][b][c][512] ----------------
__global__ void k_enter(const float* __restrict__ in, const float* __restrict__ ew,
                        const float* __restrict__ eb, u16* __restrict__ X) {
  size_t idx = (size_t)blockIdx.x * 256 + threadIdx.x;
  if (idx >= 13 * SLOTP) return;
  int t = (int)(idx / SLOTP);
  size_t r = idx % SLOTP;
  int n = (int)(r % NP);
  int c = (int)((r / NP) % C);
  int b = (int)(r / ((size_t)NP * C));
  float v = 0.f;
  if (n < NPT) {
    v = eb[c];
    if (t > 0) {
      const float* ip = in + (((size_t)b * 12 + (t - 1)) * NPT + n) * 2;
      v += ew[c * 2] * ip[0] + ew[c * 2 + 1] * ip[1];
    }
  }
  X[idx] = f2bf(v);
}

// ---------------- gated conv: grid (8, Tp, B) block (16,16) ----------------
__global__ __launch_bounds__(256) void k_gatedconv(
    const u16* __restrict__ X, u16* __restrict__ XA,
    const float* __restrict__ WFl, const float* __restrict__ bf,
    const float* __restrict__ WGl, const float* __restrict__ bg, int d) {
  __shared__ __align__(16) float wfs[8192];
  __shared__ __align__(16) float wgs[8192];
  __shared__ __align__(16) float xs[2048];
  const int tx = threadIdx.x, ty = threadIdx.y;
  const int tid = ty * 16 + tx;
  const int n0 = blockIdx.x * 64;
  const int ts = blockIdx.y;
  const int b = blockIdx.z;
  for (int i = tid; i < 8192; i += 256) {
    wfs[i] = WFl[i];
    wgs[i] = WGl[i];
  }
  v4 f[4] = {}, g[4] = {};
  for (int c0 = 0; c0 < 64; c0 += 16) {
    __syncthreads();
    for (int i2 = tid; i2 < 512; i2 += 256) {
      int nv = i2 & 15, cc = (i2 >> 4) & 15, tap = i2 >> 8;
      int n = n0 + nv * 4;
      const u16* src = &X[(size_t)(ts + tap * d) * SLOTP + ((size_t)b * C + c0 + cc) * NP + n];
      float* dst = &xs[tap * 1024 + cc * 64 + nv * 4];
      if (n + 3 < NPT) {
        ushort4 u = *(const ushort4*)src;
        dst[0] = bf2f(u.x); dst[1] = bf2f(u.y); dst[2] = bf2f(u.z); dst[3] = bf2f(u.w);
      } else {
        for (int q = 0; q < 4; ++q) dst[q] = (n + q < NPT) ? bf2f(src[q]) : 0.f;
      }
    }
    __syncthreads();
#pragma unroll
    for (int cc = 0; cc < 16; ++cc) {
      v4 xv0 = *(const v4*)&xs[cc * 64 + tx * 4];
      v4 xv1 = *(const v4*)&xs[1024 + cc * 64 + tx * 4];
      int c = c0 + cc;
      v4 wf0 = *(const v4*)&wfs[c * 64 + ty * 4];
      v4 wf1 = *(const v4*)&wfs[4096 + c * 64 + ty * 4];
      v4 wg0 = *(const v4*)&wgs[c * 64 + ty * 4];
      v4 wg1 = *(const v4*)&wgs[4096 + c * 64 + ty * 4];
#pragma unroll
      for (int r = 0; r < 4; ++r) {
        f[r] += wf0[r] * xv0 + wf1[r] * xv1;
        g[r] += wg0[r] * xv0 + wg1[r] * xv1;
      }
    }
  }
  const int cp = ty * 4;
  const int n = n0 + tx * 4;
  if (n < NPT) {
#pragma unroll
    for (int r = 0; r < 4; ++r) {
      float fb = bf[cp + r], gb2 = bg[cp + r];
      size_t ob = (size_t)ts * SLOTP + ((size_t)b * C + cp + r) * NP + n;
      ushort4 ov;
      ov.x = f2bf(tanhf(f[r][0] + fb) * sigm(g[r][0] + gb2));
      ov.y = f2bf(tanhf(f[r][1] + fb) * sigm(g[r][1] + gb2));
      ov.z = f2bf(tanhf(f[r][2] + fb) * sigm(g[r][2] + gb2));
      ov.w = f2bf(tanhf(f[r][3] + fb) * sigm(g[r][3] + gb2));
      *(ushort4*)&XA[ob] = ov;
    }
  }
}

// ---------------- skip GEMM on XA slot sslot (padded layout) ----------------
__global__ __launch_bounds__(256) void k_skip(
    const u16* __restrict__ XA, float* __restrict__ SK,
    const float* __restrict__ SWTl, const float* __restrict__ sb, int sslot) {
  __shared__ __align__(16) float wsm[4096];
  __shared__ __align__(16) float xsm[1024];
  const int tx = threadIdx.x, ty = threadIdx.y;
  const int tid = ty * 16 + tx;
  const int n0 = blockIdx.x * 64, o0 = blockIdx.y * 64, b = blockIdx.z;
  for (int i = tid; i < 1024; i += 256) {
    int c = i >> 4, ov = i & 15;
    *(v4*)&wsm[c * 64 + ov * 4] = *(const v4*)&SWTl[c * 256 + o0 + ov * 4];
  }
  v4 acc[4] = {};
  const size_t xbase = (size_t)sslot * SLOTP + (size_t)b * C * NP;
  for (int c0 = 0; c0 < 64; c0 += 16) {
    __syncthreads();
    {
      int nv = tid & 15, cc = tid >> 4;
      int n = n0 + nv * 4;
      const u16* src = &XA[xbase + (size_t)(c0 + cc) * NP + n];
      float* dst = &xsm[cc * 64 + nv * 4];
      if (n + 3 < NPT) {
        ushort4 u = *(const ushort4*)src;
        dst[0] = bf2f(u.x); dst[1] = bf2f(u.y); dst[2] = bf2f(u.z); dst[3] = bf2f(u.w);
      } else {
        for (int q = 0; q < 4; ++q) dst[q] = (n + q < NPT) ? bf2f(src[q]) : 0.f;
      }
    }
    __syncthreads();
#pragma unroll
    for (int cc = 0; cc < 16; ++cc) {
      v4 xv = *(const v4*)&xsm[cc * 64 + tx * 4];
      v4 wv = *(const v4*)&wsm[(c0 + cc) * 64 + ty * 4];
#pragma unroll
      for (int r = 0; r < 4; ++r) acc[r] += wv[r] * xv;
    }
  }
#pragma unroll
  for (int r = 0; r < 4; ++r) {
    int o = o0 + ty * 4 + r;
    float bb = sb[o];
    size_t ob = (size_t)o * (B * NPT) + (size_t)b * NPT + n0 + tx * 4;
#pragma unroll
    for (int q = 0; q < 4; ++q) {
      int n = n0 + tx * 4 + q;
      if (n < NPT) SK[ob + q] += acc[r][q] + bb;
    }
  }
}

// ---------------- MFMA diffusion + mix + residual ----------------
// grid (Tp, B), block (64,8). One block per (b,t); in-place: XOUT == XA buffer.
// Phase 1: G[n][c] = sum_m S[n][m]*X[c][m]   (A = Spad rows=n, B = XA rows=c)
// Phase 2: XG[n][o] = sum_k G[n][k]*WMX[o][k] (k = c + 64*support), + bias + residual
__global__ __launch_bounds__(512) void k_diffmix(
    const u16* __restrict__ XA, const u16* __restrict__ XIN, u16* __restrict__ XOUT,
    const u16* __restrict__ SPD, const u16* __restrict__ WMXl,
    const float* __restrict__ gb, int d) {
  __shared__ u16 G[512 * 128];  // 128 KiB, XOR-swizzled rows
  const int lane = threadIdx.x;
  const int w = threadIdx.y;
  const int t = blockIdx.x, b = blockIdx.y;
  const int lrow = lane & 15;
  const int kgrp = lane >> 4;
  const int nbase = w * 64;
  const size_t xabase = ((size_t)t * (B * C) + (size_t)b * C) * NP;

#pragma unroll 1
  for (int s = 0; s < 2; ++s) {
    v4 acc[4][4];
#pragma unroll
    for (int a = 0; a < 4; ++a)
#pragma unroll
      for (int c2 = 0; c2 < 4; ++c2) acc[a][c2] = (v4){0.f, 0.f, 0.f, 0.f};
    const u16* Sb = SPD + (size_t)s * (512 * 512);
#pragma unroll 2
    for (int k0 = 0; k0 < 512; k0 += 32) {
      const int kof = k0 + kgrp * 8;
      bf8 Af[4], Bf[4];
#pragma unroll
      for (int nt = 0; nt < 4; ++nt)
        Af[nt] = *(const bf8*)&Sb[(size_t)(nbase + nt * 16 + lrow) * 512 + kof];
#pragma unroll
      for (int ct = 0; ct < 4; ++ct)
        Bf[ct] = *(const bf8*)&XA[xabase + (size_t)(ct * 16 + lrow) * NP + kof];
#pragma unroll
      for (int nt = 0; nt < 4; ++nt)
#pragma unroll
        for (int ct = 0; ct < 4; ++ct)
          acc[nt][ct] = __builtin_amdgcn_mfma_f32_16x16x32_bf16(Af[nt], Bf[ct], acc[nt][ct], 0, 0, 0);
    }
    // dump to LDS bf16 at [n][k = s*64 + c], swizzled
#pragma unroll
    for (int nt = 0; nt < 4; ++nt)
#pragma unroll
      for (int ct = 0; ct < 4; ++ct)
#pragma unroll
        for (int r = 0; r < 4; ++r) {
          int n = nbase + nt * 16 + kgrp * 4 + r;
          int k = s * 64 + ct * 16 + lrow;
          int byte = (n << 8) + (k << 1);
          byte ^= (n & 7) << 4;
          G[byte >> 1] = f2bf(acc[nt][ct][r]);
        }
  }
  __syncthreads();
  // phase 2
  v4 acc2[4][4];
#pragma unroll
  for (int a = 0; a < 4; ++a)
#pragma unroll
    for (int c2 = 0; c2 < 4; ++c2) acc2[a][c2] = (v4){0.f, 0.f, 0.f, 0.f};
#pragma unroll
  for (int k0 = 0; k0 < 128; k0 += 32) {
    const int kof = k0 + kgrp * 8;
    bf8 Af[4], Bf[4];
#pragma unroll
    for (int nt = 0; nt < 4; ++nt) {
      int n = nbase + nt * 16 + lrow;
      int byte = (n << 8) + (kof << 1);
      byte ^= (n & 7) << 4;
      Af[nt] = *(const bf8*)&G[byte >> 1];
    }
#pragma unroll
    for (int ot = 0; ot < 4; ++ot)
      Bf[ot] = *(const bf8*)&WMXl[(size_t)(ot * 16 + lrow) * 128 + kof];
#pragma unroll
    for (int nt = 0; nt < 4; ++nt)
#pragma unroll
      for (int ot = 0; ot < 4; ++ot)
        acc2[nt][ot] = __builtin_amdgcn_mfma_f32_16x16x32_bf16(Af[nt], Bf[ot], acc2[nt][ot], 0, 0, 0);
  }
  // epilogue: + bias + residual, masked store (n0 is 4-aligned; NPT%4==0)
  const size_t rbase = ((size_t)(t + d) * (B * C) + (size_t)b * C) * NP;
#pragma unroll
  for (int nt = 0; nt < 4; ++nt) {
    int n0 = nbase + nt * 16 + kgrp * 4;
    if (n0 >= NPT) continue;
#pragma unroll
    for (int ot = 0; ot < 4; ++ot) {
      int o = ot * 16 + lrow;
      float bias = gb[o];
      ushort4 rv = *(const ushort4*)&XIN[rbase + (size_t)o * NP + n0];
      ushort4 ov;
      ov.x = f2bf(acc2[nt][ot][0] + bias + bf2f(rv.x));
      ov.y = f2bf(acc2[nt][ot][1] + bias + bf2f(rv.y));
      ov.z = f2bf(acc2[nt][ot][2] + bias + bf2f(rv.z));
      ov.w = f2bf(acc2[nt][ot][3] + bias + bf2f(rv.w));
      *(ushort4*)&XOUT[xabase + (size_t)o * NP + n0] = ov;
    }
  }
}

__global__ void k_zero(double* __restrict__ p) {
  if (threadIdx.x < 128) p[threadIdx.x] = 0.0;
}

__global__ void k_zero_sk(float* __restrict__ p) {
  size_t i = ((size_t)blockIdx.x * 256 + threadIdx.x) * 4;
  v4 z = {};
  *(v4*)&p[i] = z;
}

// ---------------- BN single-pass stats (f64), padded layout, n<500 only ----------------
__global__ void k_bnstats(const u16* __restrict__ X, double* __restrict__ st, int Tp) {
  int c = blockIdx.y;
  int perv = Tp * B * 125;
  double s = 0.0, ss = 0.0;
  for (int p = blockIdx.x * 256 + threadIdx.x; p < perv; p += 8 * 256) {
    int t = p / (B * 125);
    int r = p - t * (B * 125);
    int b = r / 125, nv = r - b * 125;
    ushort4 u = *(const ushort4*)&X[(size_t)t * SLOTP + ((size_t)b * C + c) * NP + nv * 4];
    double x0 = (double)bf2f(u.x), x1 = (double)bf2f(u.y);
    double x2 = (double)bf2f(u.z), x3 = (double)bf2f(u.w);
    s += (x0 + x1) + (x2 + x3);
    ss += (x0 * x0 + x1 * x1) + (x2 * x2 + x3 * x3);
  }
  for (int off = 32; off; off >>= 1) {
    s += __shfl_down(s, off, 64);
    ss += __shfl_down(ss, off, 64);
  }
  if ((threadIdx.x & 63) == 0) {
    atomicAdd(&st[c], s);
    atomicAdd(&st[C + c], ss);
  }
}

// ---------------- BN apply in place (padded layout, n<500) ----------------
__global__ void k_bnapply(u16* __restrict__ X, const double* __restrict__ st,
                          const float* __restrict__ gamma, const float* __restrict__ beta,
                          int Tp) {
  int idx = blockIdx.x * 256 + threadIdx.x;
  int nv = idx % 125;
  int c = (idx / 125) & 63;
  int b = (idx / 8000) & 63;
  int t = idx / 512000;
  size_t g = (size_t)t * SLOTP + ((size_t)b * C + c) * NP + nv * 4;
  double cnt = (double)Tp * (double)(B * NPT);
  double m = st[c] / cnt;
  double v = st[C + c] / cnt - m * m;
  float mean = (float)m;
  float scl = gamma[c] * rsqrtf((float)v + 1e-5f);
  float sh = beta[c];
  ushort4 u = *(const ushort4*)&X[g];
  ushort4 o;
  o.x = f2bf((bf2f(u.x) - mean) * scl + sh);
  o.y = f2bf((bf2f(u.y) - mean) * scl + sh);
  o.z = f2bf((bf2f(u.z) - mean) * scl + sh);
  o.w = f2bf((bf2f(u.w) - mean) * scl + sh);
  *(ushort4*)&X[g] = o;
}

// ---------------- head 1 ----------------
__global__ __launch_bounds__(256) void k_out1(const float* __restrict__ SK,
                                              const float* __restrict__ W1T,
                                              const float* __restrict__ b1,
                                              u16* __restrict__ H1) {
  __shared__ __align__(16) float ssm[32 * 64];
  __shared__ __align__(16) float wsm[32 * 64];
  const int tx = threadIdx.x, ty = threadIdx.y;
  const int tid = ty * 16 + tx;
  const int p0 = blockIdx.x * 64, e0 = blockIdx.y * 64;
  v4 acc[4] = {};
  for (int o0 = 0; o0 < SC; o0 += 32) {
    __syncthreads();
    for (int i = tid; i < 2048; i += 256) {
      int pp = i & 63, kk = i >> 6;
      ssm[i] = fmaxf(SK[(size_t)(o0 + kk) * (B * NPT) + p0 + pp], 0.f);
      wsm[i] = W1T[(size_t)(o0 + kk) * 512 + e0 + pp];
    }
    __syncthreads();
#pragma unroll
    for (int kk = 0; kk < 32; ++kk) {
      v4 sv = *(const v4*)&ssm[kk * 64 + tx * 4];
      v4 wv = *(const v4*)&wsm[kk * 64 + ty * 4];
#pragma unroll
      for (int r = 0; r < 4; ++r) acc[r] += wv[r] * sv;
    }
  }
#pragma unroll
  for (int r = 0; r < 4; ++r) {
    int e = e0 + ty * 4 + r;
    float bb = b1[e];
    size_t ob = (size_t)e * (B * NPT) + p0 + tx * 4;
#pragma unroll
    for (int q = 0; q < 4; ++q) H1[ob + q] = f2bf(fmaxf(acc[r][q] + bb, 0.f));
  }
}

// ---------------- head 2 ----------------
__global__ __launch_bounds__(256) void k_out2(const u16* __restrict__ H1,
                                              const float* __restrict__ W2,
                                              const float* __restrict__ b2,
                                              float* __restrict__ out) {
  int idx = blockIdx.x * 256 + threadIdx.x;
  if (idx >= B * PR * NPT) return;
  int n = idx % NPT;
  int p12 = (idx / NPT) % PR;
  int b = idx / (NPT * PR);
  size_t p = (size_t)b * NPT + n;
  const float* w = W2 + p12 * EC;
  float acc = b2[p12];
  for (int e = 0; e < EC; e += 4) {
    acc += w[e] * bf2f(H1[(size_t)e * (B * NPT) + p])
         + w[e + 1] * bf2f(H1[(size_t)(e + 1) * (B * NPT) + p])
         + w[e + 2] * bf2f(H1[(size_t)(e + 2) * (B * NPT) + p])
         + w[e + 3] * bf2f(H1[(size_t)(e + 3) * (B * NPT) + p]);
  }
  out[idx] = acc;
}

}  // namespace

extern "C" void kernel_launch(void* const* d_in, const int* in_sizes, int n_in,
                              void* d_out, int out_size, void* d_ws, size_t ws_size,
                              hipStream_t stream) {
  const float* inputs  = (const float*)d_in[0];
  const float* sup     = (const float*)d_in[1];
  const float* enter_w = (const float*)d_in[2];
  const float* enter_b = (const float*)d_in[3];
  const float* filt_w  = (const float*)d_in[4];
  const float* filt_b  = (const float*)d_in[5];
  const float* gate_w  = (const float*)d_in[6];
  const float* gate_b  = (const float*)d_in[7];
  const float* gconv_w = (const float*)d_in[8];
  const float* gconv_b = (const float*)d_in[9];
  const float* skip_w  = (const float*)d_in[10];
  const float* skip_b  = (const float*)d_in[11];
  const float* bn_g    = (const float*)d_in[12];
  const float* bn_b    = (const float*)d_in[13];
  const float* o1w     = (const float*)d_in[14];
  const float* o1b     = (const float*)d_in[15];
  const float* o2w     = (const float*)d_in[16];
  const float* o2b     = (const float*)d_in[17];
  (void)in_sizes; (void)n_in; (void)out_size;

  if (ws_size < WS_NEED) {
    k_debug_ws<<<1500, 256, 0, stream>>>((float*)d_out, (float)(ws_size >> 20));
    return;
  }

  char* base = (char*)d_ws;
  u16*    buf0 = (u16*)base;
  u16*    buf1 = (u16*)(base + SZ_BUF);
  float*  SK   = (float*)(base + OFF_SK);
  double* ST   = (double*)(base + OFF_ST);
  float*  WF   = (float*)(base + OFF_WF);
  float*  WG   = WF + 65536;
  float*  SWT  = WF + 131072;
  float*  W1T  = WF + 262144;
  u16*    WMX  = (u16*)(base + OFF_WMX);
  u16*    SPD  = (u16*)(base + OFF_SPD);

  k_prep<<<3840, 256, 0, stream>>>(filt_w, gate_w, skip_w, gconv_w, o1w, sup,
                                   WF, WG, SWT, W1T, WMX, SPD);
  k_enter<<<(int)((13 * SLOTP) / 256), 256, 0, stream>>>(inputs, enter_w, enter_b, buf0);
  k_zero_sk<<<8000, 256, 0, stream>>>(SK);

  static const int dils[8] = {1, 2, 1, 2, 1, 2, 1, 2};
  u16* bufs[2] = {buf0, buf1};
  int T = T0;
  for (int l = 0; l < 8; ++l) {
    const int d = dils[l];
    const int Tp = T - d;
    u16* XIN = bufs[l & 1];
    u16* XAb = bufs[(l + 1) & 1];  // gated staging, then overwritten in-place by diffmix
    k_gatedconv<<<dim3(8, Tp, B), dim3(16, 16), 0, stream>>>(
        XIN, XAb, WF + l * 8192, filt_b + l * 64, WG + l * 8192, gate_b + l * 64, d);
    k_skip<<<dim3(8, 4, B), dim3(16, 16), 0, stream>>>(
        XAb, SK, SWT + l * 16384, skip_b + l * 256, Tp - 1);
    k_diffmix<<<dim3(Tp, B), dim3(64, 8), 0, stream>>>(
        XAb, XIN, XAb, SPD, WMX + l * 8192, gconv_b + l * 64, d);
    k_zero<<<1, 128, 0, stream>>>(ST);
    k_bnstats<<<dim3(8, C), 256, 0, stream>>>(XAb, ST, Tp);
    k_bnapply<<<Tp * 2000, 256, 0, stream>>>(XAb, ST, bn_g + l * 64, bn_b + l * 64, Tp);
    T = Tp;
  }

  u16* H1 = buf1;  // layer-7 input buffer, dead after the loop
  k_out1<<<dim3(500, 8), dim3(16, 16), 0, stream>>>(SK, W1T, o1b, H1);
  k_out2<<<1500, 256, 0, stream>>>(H1, o2w, o2b, (float*)d_out);
}

// Round 8
// 2312.718 us; speedup vs baseline: 6.1997x; 1.5485x over previous
//
#include <hip/hip_runtime.h>

typedef float v4 __attribute__((ext_vector_type(4)));
typedef short bf8 __attribute__((ext_vector_type(8)));  // 8 bf16 in 4 VGPRs
typedef unsigned short u16;
typedef unsigned int u32;

#define DEVI __device__ __forceinline__

namespace {

constexpr int B = 64, C = 64, NPT = 500, NP = 512, T0 = 13, SC = 256, EC = 512, PR = 12;
constexpr size_t SLOTP = (size_t)B * C * NP;  // elems per padded time slice

// byte offsets in d_ws
constexpr size_t SZ_BUF  = 13 * SLOTP * 2;              // 54,525,952 per x buffer (bf16)
constexpr size_t OFF_SK  = 2 * SZ_BUF;                  // f32 [256][B*NPT]
constexpr size_t SZ_SK   = (size_t)SC * B * NPT * 4;    // 32,768,000
constexpr size_t OFF_ST  = OFF_SK + SZ_SK;              // f64[128] BN raw stats
constexpr size_t OFF_STP = OFF_ST + 1024;               // f32[192] BN params (mean,scl,sh)
constexpr size_t OFF_W1T = OFF_STP + 1024;              // f32[131072]
constexpr size_t OFF_WMX = OFF_W1T + (size_t)131072*4;  // u16[65536]  gconv w bf16
constexpr size_t OFF_WFB = OFF_WMX + (size_t)65536*2;   // u16[65536]  filter w bf16 [l][cp][k128]
constexpr size_t OFF_WGB = OFF_WFB + (size_t)65536*2;   // u16[65536]  gate w bf16
constexpr size_t OFF_SWB = OFF_WGB + (size_t)65536*2;   // u16[131072] skip w bf16 [l][o][c]
constexpr size_t OFF_SPD = OFF_SWB + (size_t)131072*2;  // u16[524288] supports padded bf16
constexpr size_t WS_NEED = OFF_SPD + (size_t)524288*2;  // 144,050,176

DEVI float sigm(float x) { return 1.f / (1.f + expf(-x)); }
DEVI float bf2f(u16 u) { u32 x = ((u32)u) << 16; float f; __builtin_memcpy(&f, &x, 4); return f; }
DEVI u16 f2bf(float f) { u32 x; __builtin_memcpy(&x, &f, 4); return (u16)((x + 0x7FFF + ((x >> 16) & 1)) >> 16); }
// A-tile [n512][k128] bf16; XOR picked so 16-consecutive-n fragment reads are 2-way (free),
// transpose writes (n = 8*lane+j) spread over 8 banks.
DEVI int swzA(int n, int k) { int byte = (n << 8) + (k << 1); byte ^= (((n >> 1) ^ (n >> 3)) & 7) << 4; return byte; }
// skip tile [n512][cp64] bf16, same swizzle family
DEVI int swzS(int n, int cp) { int byte = (n << 7) + (cp << 1); byte ^= (((n >> 1) ^ (n >> 3)) & 7) << 4; return byte; }

__global__ void k_debug_ws(float* __restrict__ out, float val) {
  int i = blockIdx.x * 256 + threadIdx.x;
  if (i < B * PR * NPT) out[i] = val;
}

// ---------------- weight repack + param init (every call: ws is re-poisoned) ----------------
__global__ void k_prep(const float* __restrict__ fw, const float* __restrict__ gw,
                       const float* __restrict__ sw, const float* __restrict__ gcw,
                       const float* __restrict__ o1w, const float* __restrict__ sup,
                       u16* __restrict__ WFB, u16* __restrict__ WGB,
                       u16* __restrict__ SWB, u16* __restrict__ WMX,
                       float* __restrict__ W1T, u16* __restrict__ SPD,
                       float* __restrict__ STP, double* __restrict__ ST) {
  int i = blockIdx.x * 256 + threadIdx.x;
  if (i < 65536) {  // WFB/WGB[l][cp][k=tap*64+c]
    int k = i & 127, cp = (i >> 7) & 63, l = i >> 13;
    int tap = k >> 6, c = k & 63;
    int g = ((l * 64 + cp) * 64 + c) * 2 + tap;
    WFB[i] = f2bf(fw[g]);
    WGB[i] = f2bf(gw[g]);
  }
  int j = i - 65536;
  if (j >= 0 && j < 131072) {  // SWB[l][o][c]
    int c = j & 63, o = (j >> 6) & 255, l = j >> 14;
    SWB[j] = f2bf(sw[(l * 256 + o) * 64 + c]);
  }
  int k2 = i - 196608;
  if (k2 >= 0 && k2 < 65536) WMX[k2] = f2bf(gcw[k2]);  // identical index order
  int m = i - 262144;
  if (m >= 0 && m < 131072) {  // W1T[o][e]
    int e = m & 511, o = m >> 9;
    W1T[m] = o1w[e * 256 + o];
  }
  int sp = i - 393216;
  if (sp >= 0 && sp < 524288) {  // SPD[s][n512][m512] zero-padded bf16
    int mm = sp & 511, n = (sp >> 9) & 511, s = sp >> 18;
    float v = (n < NPT && mm < NPT) ? sup[(size_t)s * NPT * NPT + (size_t)n * NPT + mm] : 0.f;
    SPD[sp] = f2bf(v);
  }
  int q = i - 917504;
  if (q >= 0 && q < 192) STP[q] = (q >= 64 && q < 128) ? 1.f : 0.f;  // identity BN for layer 0
  int z = i - 917696;
  if (z >= 0 && z < 128) ST[z] = 0.0;
}

// ---------------- enter: [B,12,N,2] -> Xbf[t][b][c][512], t=0 is left-pad, n pad zero ----------------
__global__ void k_enter(const float* __restrict__ in, const float* __restrict__ ew,
                        const float* __restrict__ eb, u16* __restrict__ X) {
  size_t idx = (size_t)blockIdx.x * 256 + threadIdx.x;
  if (idx >= 13 * SLOTP) return;
  int t = (int)(idx / SLOTP);
  size_t r = idx % SLOTP;
  int n = (int)(r % NP);
  int c = (int)((r / NP) % C);
  int b = (int)(r / ((size_t)NP * C));
  float v = 0.f;
  if (n < NPT) {
    v = eb[c];
    if (t > 0) {
      const float* ip = in + (((size_t)b * 12 + (t - 1)) * NPT + n) * 2;
      v += ew[c * 2] * ip[0] + ew[c * 2 + 1] * ip[1];
    }
  }
  X[idx] = f2bf(v);
}

__global__ void k_zero_sk(float* __restrict__ p) {
  size_t i = ((size_t)blockIdx.x * 256 + threadIdx.x) * 4;
  v4 z = {};
  *(v4*)&p[i] = z;
}

// ---------------- MFMA gated conv + fused BN-on-read + fused skip GEMM ----------------
// grid (Tp, B), block (64,8). out XA[c][n] = tanh(F)*sigm(G); skip at t==Tp-1.
__global__ __launch_bounds__(512) void k_gatedconv(
    const u16* __restrict__ X, u16* __restrict__ XA,
    const float* __restrict__ STP,
    const u16* __restrict__ WFl, const float* __restrict__ bfb,
    const u16* __restrict__ WGl, const float* __restrict__ bgb,
    const u16* __restrict__ SWl, const float* __restrict__ sb,
    float* __restrict__ SK, int d, int Tp) {
  __shared__ u16 L[65536];  // 128 KiB
  const int lane = threadIdx.x, w = threadIdx.y;
  const int tid = w * 64 + lane;
  const int t = blockIdx.x, b = blockIdx.y;
  const int lrow = lane & 15, kgrp = lane >> 4;
  const int nbase = w * 64;

  // stage + transpose + BN-on-read: L[n][k=tap*64+c] = bn(X[t+tap*d][b][c][n])
  for (int i = tid; i < 8192; i += 512) {
    int tap = i >> 12;
    int c = (i >> 6) & 63;
    int n0 = (i & 63) * 8;
    const u16* src = &X[(size_t)(t + tap * d) * SLOTP + ((size_t)b * C + c) * NP + n0];
    float mean = STP[c], scl = STP[64 + c], sh = STP[128 + c];
    ushort4 a = *(const ushort4*)src;
    ushort4 a2 = *(const ushort4*)(src + 4);
    u16 vals[8] = {a.x, a.y, a.z, a.w, a2.x, a2.y, a2.z, a2.w};
    int k = tap * 64 + c;
#pragma unroll
    for (int jj = 0; jj < 8; ++jj) {
      int n = n0 + jj;
      L[swzA(n, k) >> 1] = f2bf((bf2f(vals[jj]) - mean) * scl + sh);
    }
  }
  __syncthreads();

  v4 af[4][4], ag[4][4];
#pragma unroll
  for (int a1 = 0; a1 < 4; ++a1)
#pragma unroll
    for (int a2 = 0; a2 < 4; ++a2) { af[a1][a2] = (v4){0.f,0.f,0.f,0.f}; ag[a1][a2] = (v4){0.f,0.f,0.f,0.f}; }

#pragma unroll
  for (int k0 = 0; k0 < 128; k0 += 32) {
    const int kof = k0 + kgrp * 8;
    bf8 Av[4];
#pragma unroll
    for (int nt = 0; nt < 4; ++nt) {
      int n = nbase + nt * 16 + lrow;
      Av[nt] = *(const bf8*)&L[swzA(n, kof) >> 1];
    }
#pragma unroll
    for (int ct = 0; ct < 4; ++ct) {
      bf8 Fw = *(const bf8*)&WFl[(size_t)(ct * 16 + lrow) * 128 + kof];
      bf8 Gw = *(const bf8*)&WGl[(size_t)(ct * 16 + lrow) * 128 + kof];
#pragma unroll
      for (int nt = 0; nt < 4; ++nt) {
        af[nt][ct] = __builtin_amdgcn_mfma_f32_16x16x32_bf16(Av[nt], Fw, af[nt][ct], 0, 0, 0);
        ag[nt][ct] = __builtin_amdgcn_mfma_f32_16x16x32_bf16(Av[nt], Gw, ag[nt][ct], 0, 0, 0);
      }
    }
  }

  // epilogue: activation, store XA[cp][n] (rows n in lane, col cp)
  const size_t xab = (size_t)t * SLOTP + (size_t)b * C * NP;
  ushort4 ovv[4][4];
#pragma unroll
  for (int nt = 0; nt < 4; ++nt) {
    int n0s = nbase + nt * 16 + kgrp * 4;
#pragma unroll
    for (int ct = 0; ct < 4; ++ct) {
      int cp = ct * 16 + lrow;
      float fb = bfb[cp], gb2 = bgb[cp];
      ushort4 ov;
      ov.x = f2bf(tanhf(af[nt][ct][0] + fb) * sigm(ag[nt][ct][0] + gb2));
      ov.y = f2bf(tanhf(af[nt][ct][1] + fb) * sigm(ag[nt][ct][1] + gb2));
      ov.z = f2bf(tanhf(af[nt][ct][2] + fb) * sigm(ag[nt][ct][2] + gb2));
      ov.w = f2bf(tanhf(af[nt][ct][3] + fb) * sigm(ag[nt][ct][3] + gb2));
      ovv[nt][ct] = ov;
      if (n0s < NPT) *(ushort4*)&XA[xab + (size_t)cp * NP + n0s] = ov;
    }
  }

  // fused skip GEMM on the layer's last slice: SK[o][b*N+n] += sb[o] + sum_c sw[o][c]*XA[c][n]
  if (t == Tp - 1) {
    __syncthreads();  // all MFMA reads of L done
#pragma unroll
    for (int nt = 0; nt < 4; ++nt) {
      int n0s = nbase + nt * 16 + kgrp * 4;
#pragma unroll
      for (int ct = 0; ct < 4; ++ct) {
        int cp = ct * 16 + lrow;
        ushort4 ov = ovv[nt][ct];
        L[swzS(n0s + 0, cp) >> 1] = ov.x;
        L[swzS(n0s + 1, cp) >> 1] = ov.y;
        L[swzS(n0s + 2, cp) >> 1] = ov.z;
        L[swzS(n0s + 3, cp) >> 1] = ov.w;
      }
    }
    __syncthreads();
#pragma unroll 1
    for (int ot = 0; ot < 16; ++ot) {
      v4 a[4];
#pragma unroll
      for (int nt = 0; nt < 4; ++nt) a[nt] = (v4){0.f,0.f,0.f,0.f};
#pragma unroll
      for (int k0 = 0; k0 < 64; k0 += 32) {
        const int kof = k0 + kgrp * 8;
        bf8 Bs = *(const bf8*)&SWl[(size_t)(ot * 16 + lrow) * 64 + kof];
#pragma unroll
        for (int nt = 0; nt < 4; ++nt) {
          int n = nbase + nt * 16 + lrow;
          bf8 Av2 = *(const bf8*)&L[swzS(n, kof) >> 1];
          a[nt] = __builtin_amdgcn_mfma_f32_16x16x32_bf16(Av2, Bs, a[nt], 0, 0, 0);
        }
      }
      int o = ot * 16 + lrow;
      float bb = sb[o];
#pragma unroll
      for (int nt = 0; nt < 4; ++nt) {
        int n0s = nbase + nt * 16 + kgrp * 4;
        if (n0s < NPT) {
          float* dst = &SK[(size_t)o * (B * NPT) + (size_t)b * NPT + n0s];
          v4 old = *(const v4*)dst;
          *(v4*)dst = old + a[nt] + bb;
        }
      }
    }
  }
}

// ---------------- MFMA diffusion + mix + BN'd residual; in-place XOUT == XA ----------------
__global__ __launch_bounds__(512) void k_diffmix(
    const u16* __restrict__ XA, const u16* __restrict__ XIN, u16* __restrict__ XOUT,
    const u16* __restrict__ SPD, const u16* __restrict__ WMXl,
    const float* __restrict__ gb, const float* __restrict__ STP, int d) {
  __shared__ u16 G[512 * 128];  // 128 KiB
  const int lane = threadIdx.x;
  const int w = threadIdx.y;
  const int t = blockIdx.x, b = blockIdx.y;
  const int lrow = lane & 15;
  const int kgrp = lane >> 4;
  const int nbase = w * 64;
  const size_t xabase = ((size_t)t * (B * C) + (size_t)b * C) * NP;

#pragma unroll 1
  for (int s = 0; s < 2; ++s) {
    v4 acc[4][4];
#pragma unroll
    for (int a = 0; a < 4; ++a)
#pragma unroll
      for (int c2 = 0; c2 < 4; ++c2) acc[a][c2] = (v4){0.f, 0.f, 0.f, 0.f};
    const u16* Sb = SPD + (size_t)s * (512 * 512);
#pragma unroll 2
    for (int k0 = 0; k0 < 512; k0 += 32) {
      const int kof = k0 + kgrp * 8;
      bf8 Af[4], Bf[4];
#pragma unroll
      for (int nt = 0; nt < 4; ++nt)
        Af[nt] = *(const bf8*)&Sb[(size_t)(nbase + nt * 16 + lrow) * 512 + kof];
#pragma unroll
      for (int ct = 0; ct < 4; ++ct)
        Bf[ct] = *(const bf8*)&XA[xabase + (size_t)(ct * 16 + lrow) * NP + kof];
#pragma unroll
      for (int nt = 0; nt < 4; ++nt)
#pragma unroll
        for (int ct = 0; ct < 4; ++ct)
          acc[nt][ct] = __builtin_amdgcn_mfma_f32_16x16x32_bf16(Af[nt], Bf[ct], acc[nt][ct], 0, 0, 0);
    }
#pragma unroll
    for (int nt = 0; nt < 4; ++nt)
#pragma unroll
      for (int ct = 0; ct < 4; ++ct)
#pragma unroll
        for (int r = 0; r < 4; ++r) {
          int n = nbase + nt * 16 + kgrp * 4 + r;
          int k = s * 64 + ct * 16 + lrow;
          int byte = (n << 8) + (k << 1);
          byte ^= (n & 7) << 4;
          G[byte >> 1] = f2bf(acc[nt][ct][r]);
        }
  }
  __syncthreads();
  v4 acc2[4][4];
#pragma unroll
  for (int a = 0; a < 4; ++a)
#pragma unroll
    for (int c2 = 0; c2 < 4; ++c2) acc2[a][c2] = (v4){0.f, 0.f, 0.f, 0.f};
#pragma unroll
  for (int k0 = 0; k0 < 128; k0 += 32) {
    const int kof = k0 + kgrp * 8;
    bf8 Af[4], Bf[4];
#pragma unroll
    for (int nt = 0; nt < 4; ++nt) {
      int n = nbase + nt * 16 + lrow;
      int byte = (n << 8) + (kof << 1);
      byte ^= (n & 7) << 4;
      Af[nt] = *(const bf8*)&G[byte >> 1];
    }
#pragma unroll
    for (int ot = 0; ot < 4; ++ot)
      Bf[ot] = *(const bf8*)&WMXl[(size_t)(ot * 16 + lrow) * 128 + kof];
#pragma unroll
    for (int nt = 0; nt < 4; ++nt)
#pragma unroll
      for (int ot = 0; ot < 4; ++ot)
        acc2[nt][ot] = __builtin_amdgcn_mfma_f32_16x16x32_bf16(Af[nt], Bf[ot], acc2[nt][ot], 0, 0, 0);
  }
  const size_t rbase = ((size_t)(t + d) * (B * C) + (size_t)b * C) * NP;
#pragma unroll
  for (int nt = 0; nt < 4; ++nt) {
    int n0 = nbase + nt * 16 + kgrp * 4;
    if (n0 >= NPT) continue;
#pragma unroll
    for (int ot = 0; ot < 4; ++ot) {
      int o = ot * 16 + lrow;
      float bias = gb[o];
      float m = STP[o], s2 = STP[64 + o], h = STP[128 + o];
      ushort4 rv = *(const ushort4*)&XIN[rbase + (size_t)o * NP + n0];
      ushort4 ov;
      ov.x = f2bf(acc2[nt][ot][0] + bias + (bf2f(rv.x) - m) * s2 + h);
      ov.y = f2bf(acc2[nt][ot][1] + bias + (bf2f(rv.y) - m) * s2 + h);
      ov.z = f2bf(acc2[nt][ot][2] + bias + (bf2f(rv.z) - m) * s2 + h);
      ov.w = f2bf(acc2[nt][ot][3] + bias + (bf2f(rv.w) - m) * s2 + h);
      *(ushort4*)&XOUT[xabase + (size_t)o * NP + n0] = ov;
    }
  }
}

// ---------------- BN stats (f64 sum/sumsq) on raw x, n<500 ----------------
__global__ void k_bnstats(const u16* __restrict__ X, double* __restrict__ st, int Tp) {
  int c = blockIdx.y;
  int perv = Tp * B * 125;
  double s = 0.0, ss = 0.0;
  for (int p = blockIdx.x * 256 + threadIdx.x; p < perv; p += 8 * 256) {
    int t = p / (B * 125);
    int r = p - t * (B * 125);
    int b = r / 125, nv = r - b * 125;
    ushort4 u = *(const ushort4*)&X[(size_t)t * SLOTP + ((size_t)b * C + c) * NP + nv * 4];
    double x0 = (double)bf2f(u.x), x1 = (double)bf2f(u.y);
    double x2 = (double)bf2f(u.z), x3 = (double)bf2f(u.w);
    s += (x0 + x1) + (x2 + x3);
    ss += (x0 * x0 + x1 * x1) + (x2 * x2 + x3 * x3);
  }
  for (int off = 32; off; off >>= 1) {
    s += __shfl_down(s, off, 64);
    ss += __shfl_down(ss, off, 64);
  }
  if ((threadIdx.x & 63) == 0) {
    atomicAdd(&st[c], s);
    atomicAdd(&st[C + c], ss);
  }
}

// ---------------- finalize BN params for the next layer; re-zero stats ----------------
__global__ void k_bnfin(double* __restrict__ st, float* __restrict__ stp,
                        const float* __restrict__ gamma, const float* __restrict__ beta, int Tp) {
  int c = threadIdx.x;
  if (c < C) {
    double cnt = (double)Tp * (double)(B * NPT);
    double m = st[c] / cnt;
    double v = st[C + c] / cnt - m * m;
    stp[c] = (float)m;
    stp[C + c] = gamma[c] * rsqrtf((float)v + 1e-5f);
    stp[2 * C + c] = beta[c];
    st[c] = 0.0;
    st[C + c] = 0.0;
  }
}

// ---------------- head 1 ----------------
__global__ __launch_bounds__(256) void k_out1(const float* __restrict__ SK,
                                              const float* __restrict__ W1T,
                                              const float* __restrict__ b1,
                                              u16* __restrict__ H1) {
  __shared__ __align__(16) float ssm[32 * 64];
  __shared__ __align__(16) float wsm[32 * 64];
  const int tx = threadIdx.x, ty = threadIdx.y;
  const int tid = ty * 16 + tx;
  const int p0 = blockIdx.x * 64, e0 = blockIdx.y * 64;
  v4 acc[4] = {};
  for (int o0 = 0; o0 < SC; o0 += 32) {
    __syncthreads();
    for (int i = tid; i < 2048; i += 256) {
      int pp = i & 63, kk = i >> 6;
      ssm[i] = fmaxf(SK[(size_t)(o0 + kk) * (B * NPT) + p0 + pp], 0.f);
      wsm[i] = W1T[(size_t)(o0 + kk) * 512 + e0 + pp];
    }
    __syncthreads();
#pragma unroll
    for (int kk = 0; kk < 32; ++kk) {
      v4 sv = *(const v4*)&ssm[kk * 64 + tx * 4];
      v4 wv = *(const v4*)&wsm[kk * 64 + ty * 4];
#pragma unroll
      for (int r = 0; r < 4; ++r) acc[r] += wv[r] * sv;
    }
  }
#pragma unroll
  for (int r = 0; r < 4; ++r) {
    int e = e0 + ty * 4 + r;
    float bb = b1[e];
    size_t ob = (size_t)e * (B * NPT) + p0 + tx * 4;
#pragma unroll
    for (int q = 0; q < 4; ++q) H1[ob + q] = f2bf(fmaxf(acc[r][q] + bb, 0.f));
  }
}

// ---------------- head 2 ----------------
__global__ __launch_bounds__(256) void k_out2(const u16* __restrict__ H1,
                                              const float* __restrict__ W2,
                                              const float* __restrict__ b2,
                                              float* __restrict__ out) {
  int idx = blockIdx.x * 256 + threadIdx.x;
  if (idx >= B * PR * NPT) return;
  int n = idx % NPT;
  int p12 = (idx / NPT) % PR;
  int b = idx / (NPT * PR);
  size_t p = (size_t)b * NPT + n;
  const float* w = W2 + p12 * EC;
  float acc = b2[p12];
  for (int e = 0; e < EC; e += 4) {
    acc += w[e] * bf2f(H1[(size_t)e * (B * NPT) + p])
         + w[e + 1] * bf2f(H1[(size_t)(e + 1) * (B * NPT) + p])
         + w[e + 2] * bf2f(H1[(size_t)(e + 2) * (B * NPT) + p])
         + w[e + 3] * bf2f(H1[(size_t)(e + 3) * (B * NPT) + p]);
  }
  out[idx] = acc;
}

}  // namespace

extern "C" void kernel_launch(void* const* d_in, const int* in_sizes, int n_in,
                              void* d_out, int out_size, void* d_ws, size_t ws_size,
                              hipStream_t stream) {
  const float* inputs  = (const float*)d_in[0];
  const float* sup     = (const float*)d_in[1];
  const float* enter_w = (const float*)d_in[2];
  const float* enter_b = (const float*)d_in[3];
  const float* filt_w  = (const float*)d_in[4];
  const float* filt_b  = (const float*)d_in[5];
  const float* gate_w  = (const float*)d_in[6];
  const float* gate_b  = (const float*)d_in[7];
  const float* gconv_w = (const float*)d_in[8];
  const float* gconv_b = (const float*)d_in[9];
  const float* skip_w  = (const float*)d_in[10];
  const float* skip_b  = (const float*)d_in[11];
  const float* bn_g    = (const float*)d_in[12];
  const float* bn_b    = (const float*)d_in[13];
  const float* o1w     = (const float*)d_in[14];
  const float* o1b     = (const float*)d_in[15];
  const float* o2w     = (const float*)d_in[16];
  const float* o2b     = (const float*)d_in[17];
  (void)in_sizes; (void)n_in; (void)out_size;

  if (ws_size < WS_NEED) {
    k_debug_ws<<<1500, 256, 0, stream>>>((float*)d_out, (float)(ws_size >> 20));
    return;
  }

  char* base = (char*)d_ws;
  u16*    buf0 = (u16*)base;
  u16*    buf1 = (u16*)(base + SZ_BUF);
  float*  SK   = (float*)(base + OFF_SK);
  double* ST   = (double*)(base + OFF_ST);
  float*  STP  = (float*)(base + OFF_STP);
  float*  W1T  = (float*)(base + OFF_W1T);
  u16*    WMX  = (u16*)(base + OFF_WMX);
  u16*    WFB  = (u16*)(base + OFF_WFB);
  u16*    WGB  = (u16*)(base + OFF_WGB);
  u16*    SWB  = (u16*)(base + OFF_SWB);
  u16*    SPD  = (u16*)(base + OFF_SPD);

  k_prep<<<3586, 256, 0, stream>>>(filt_w, gate_w, skip_w, gconv_w, o1w, sup,
                                   WFB, WGB, SWB, WMX, W1T, SPD, STP, ST);
  k_enter<<<(int)((13 * SLOTP) / 256), 256, 0, stream>>>(inputs, enter_w, enter_b, buf0);
  k_zero_sk<<<8000, 256, 0, stream>>>(SK);

  static const int dils[8] = {1, 2, 1, 2, 1, 2, 1, 2};
  u16* bufs[2] = {buf0, buf1};
  int T = T0;
  for (int l = 0; l < 8; ++l) {
    const int d = dils[l];
    const int Tp = T - d;
    u16* XIN = bufs[l & 1];
    u16* XAb = bufs[(l + 1) & 1];
    k_gatedconv<<<dim3(Tp, B), dim3(64, 8), 0, stream>>>(
        XIN, XAb, STP, WFB + l * 8192, filt_b + l * 64, WGB + l * 8192, gate_b + l * 64,
        SWB + l * 16384, skip_b + l * 256, SK, d, Tp);
    if (l < 7) {
      k_diffmix<<<dim3(Tp, B), dim3(64, 8), 0, stream>>>(
          XAb, XIN, XAb, SPD, WMX + l * 8192, gconv_b + l * 64, STP, d);
      k_bnstats<<<dim3(8, C), 256, 0, stream>>>(XAb, ST, Tp);
      k_bnfin<<<1, 64, 0, stream>>>(ST, STP, bn_g + l * 64, bn_b + l * 64, Tp);
    }
    T = Tp;
  }

  u16* H1 = buf1;  // dead after the loop (last x_out landed in buf0)
  k_out1<<<dim3(500, 8), dim3(16, 16), 0, stream>>>(SK, W1T, o1b, H1);
  k_out2<<<1500, 256, 0, stream>>>(H1, o2w, o2b, (float*)d_out);
}